// Round 4
// baseline (261.581 us; speedup 1.0000x reference)
//
#include <hip/hip_runtime.h>
#include <hip/hip_bf16.h>

// Problem constants: B=2, S=2048, D=1024, H=16, HD=64
#define B_  2
#define S_  2048
#define D_  1024
#define H_  16
#define HD_ 64

using bf16x8  = __attribute__((ext_vector_type(8))) __bf16;
using floatx4 = __attribute__((ext_vector_type(4))) float;
using intx4   = __attribute__((ext_vector_type(4))) int;

__device__ __forceinline__ unsigned short f2bf(float f) {
  union { float f; unsigned int i; } v; v.f = f;
  unsigned int r = v.i + 0x7fffu + ((v.i >> 16) & 1u);   // RNE
  return (unsigned short)(r >> 16);
}
// packed f32x2 -> bf16x2 (v_cvt_pk_bf16_f32 on gfx950; header fallback = same RNE)
__device__ __forceinline__ unsigned int f2bf_pk(float a, float b) {
  union { __hip_bfloat162 h2; unsigned int u; } c;
  c.h2 = __float22bfloat162_rn(make_float2(a, b));
  return c.u;   // low 16 = a, high 16 = b
}
__device__ __forceinline__ floatx4 mfma16(bf16x8 a, bf16x8 b, floatx4 c) {
  return __builtin_amdgcn_mfma_f32_16x16x32_bf16(a, b, c, 0, 0, 0);
}
// async global->LDS, 16B/lane; LDS dest = wave-uniform base + lane*16
__device__ __forceinline__ void gld16(const unsigned short* g, unsigned short* l) {
  __builtin_amdgcn_global_load_lds(
      (const __attribute__((address_space(1))) unsigned int*)g,
      (__attribute__((address_space(3))) unsigned int*)l, 16, 0, 0);
}
// native exp2 (scores are pre-scaled by log2e in GEMM1's qscale)
#if __has_builtin(__builtin_amdgcn_exp2f)
#define EXP2(x) __builtin_amdgcn_exp2f(x)
#else
#define EXP2(x) __expf((x) * 0.6931471805599453f)
#endif
// single-bit sign-extended extract: 0 or -1
#if __has_builtin(__builtin_amdgcn_sbfe)
#define SBFE1(x, o) __builtin_amdgcn_sbfe((int)(x), (o), 1)
#else
#define SBFE1(x, o) (((int)((x) << (31 - (o)))) >> 31)
#endif
// swizzles: ushort offset of 8-ushort group within a row
#define SW8(row, g) ((((g) ^ ((row) & 7)) * 8))          // 64-ushort rows
#define SW4(row, g) ((((g) ^ (((row) >> 1) & 3)) * 8))   // 32-ushort rows
// K-row permutation: LDS row r holds token TAU(r); bits (b5,b4,b3,b2,b1,b0) ->
// (b5,b3,b2,b4,b1,b0). Makes swapped-QK^T score layout == PV A-frag layout.
#define TAU(r) (((r) & 0x23) | (((r) & 0x08) << 1) | (((r) & 0x04) << 1) | (((r) & 0x10) >> 2))

// 0.125 (1/sqrt(HD)) * log2(e): folded so attn uses raw v_exp_f32 (exp2)
#define QSCALE 0.18033688011f

// ---------------------------------------------------------------------------
// prep: one dispatch doing all pre-passes (launch-overhead fusion).
// blocks [0,2048): cvt x | [2048,3072): cvt w_in[0:2048] | [3072,3584): cvt
// w_out | [3584,5632): mask->bitpack | [5632,6656): V transpose to [B][H][HD][S]
// ---------------------------------------------------------------------------
__global__ __launch_bounds__(256) void prep_kernel(
    const float* __restrict__ x, const float* __restrict__ w_in,
    const float* __restrict__ w_out, const float* __restrict__ V,
    const float* __restrict__ Mm,
    unsigned short* __restrict__ xb, unsigned short* __restrict__ wb,
    unsigned short* __restrict__ wob, unsigned short* __restrict__ vt,
    unsigned long long* __restrict__ mpk)
{
  __shared__ unsigned short tile[64 * 72];
  const int bid = blockIdx.x, tid = threadIdx.x;

  if (bid < 3584) {                       // bulk fp32->bf16 converts
    const float* src; unsigned short* dst; int base;
    if (bid < 2048)      { src = x;     dst = xb;  base = bid; }
    else if (bid < 3072) { src = w_in;  dst = wb;  base = bid - 2048; }
    else                 { src = w_out; dst = wob; base = bid - 3072; }
    const int i = (base * 256 + tid) * 8;
    float4 a = *(const float4*)(src + i);
    float4 b = *(const float4*)(src + i + 4);
    union { unsigned int w[4]; intx4 v; } o;
    o.w[0] = f2bf_pk(a.x, a.y); o.w[1] = f2bf_pk(a.z, a.w);
    o.w[2] = f2bf_pk(b.x, b.y); o.w[3] = f2bf_pk(b.z, b.w);
    *(intx4*)(dst + i) = o.v;
  } else if (bid < 5632) {                // mask bit-pack, 64 words/block
    const int wave = tid >> 6, lane = tid & 63;
    const int w0 = (bid - 3584) * 64 + wave * 16;
#pragma unroll 4
    for (int j = 0; j < 16; ++j) {
      float v = Mm[(size_t)(w0 + j) * 64 + lane];
      unsigned long long bl = __ballot(v != 0.0f);
      if (lane == 0) mpk[w0 + j] = bl;
    }
  } else {                                 // V transpose (b,h,64-token tile)
    const int idx = bid - 5632;
    const int t0 = (idx & 31) * 64, h = (idx >> 5) & 15, b = idx >> 9;
    const int sr = tid >> 3, sc = (tid & 7) * 8;
    const float* src = V + ((size_t)((b * S_ + t0) * H_ + h)) * HD_;
#pragma unroll
    for (int half = 0; half < 2; ++half) {
      const int r = sr + half * 32;
      float4 v0 = *(const float4*)&src[(size_t)r * (H_ * HD_) + sc];
      float4 v1 = *(const float4*)&src[(size_t)r * (H_ * HD_) + sc + 4];
      union { unsigned int w[4]; intx4 v; } p;
      p.w[0] = f2bf_pk(v0.x, v0.y); p.w[1] = f2bf_pk(v0.z, v0.w);
      p.w[2] = f2bf_pk(v1.x, v1.y); p.w[3] = f2bf_pk(v1.z, v1.w);
      *(intx4*)&tile[r * 72 + sc] = p.v;
    }
    __syncthreads();
    unsigned short* dst = vt + ((size_t)((b * H_ + h) * HD_)) * S_ + t0;
    union { unsigned short u[8]; intx4 v; } pack;
#pragma unroll
    for (int j = 0; j < 8; ++j) pack.u[j] = tile[(sc + j) * 72 + sr];
    *(intx4*)&dst[(size_t)sr * S_ + sc] = pack.v;
#pragma unroll
    for (int j = 0; j < 8; ++j) pack.u[j] = tile[(sc + j) * 72 + sr + 32];
    *(intx4*)&dst[(size_t)(sr + 32) * S_ + sc] = pack.v;
  }
}

// ---------------------------------------------------------------------------
// bf16 MFMA GEMM (m97-style): C = A @ Bm^T + bias. 128x128, BK=32,
// global_load_lds + XOR-swizzled LDS. qscale: cols<1024 *= QSCALE.
// ---------------------------------------------------------------------------
__global__ __launch_bounds__(256) void gemm_abt(
    const unsigned short* __restrict__ A,
    const unsigned short* __restrict__ Bm,
    const float* __restrict__ bias,
    unsigned short* __restrict__ Cb, float* __restrict__ Cf,
    int M, int N, int K, int qscale)
{
  __shared__ unsigned short As[128 * 32];
  __shared__ unsigned short Bs[128 * 32];

  const int tid  = threadIdx.x;
  const int wave = tid >> 6, lane = tid & 63;
  const int quad = lane >> 4, l15 = lane & 15;
  const int wr = wave >> 1, wc = wave & 1;
  const int bm = blockIdx.y * 128, bn = blockIdx.x * 128;
  const int srow = tid >> 2, gs = tid & 3;

  floatx4 acc[4][4];
#pragma unroll
  for (int mt = 0; mt < 4; ++mt)
#pragma unroll
    for (int nt = 0; nt < 4; ++nt)
      acc[mt][nt] = (floatx4){0.f, 0.f, 0.f, 0.f};

  for (int k0 = 0; k0 < K; k0 += 32) {
    __syncthreads();
#pragma unroll
    for (int r = 0; r < 2; ++r) {
      const int row = srow + r * 64;
      gld16(&A[(size_t)(bm + row) * K + k0 + SW4(row, gs)],
            &As[wave * 512 + r * 2048]);
      gld16(&Bm[(size_t)(bn + row) * K + k0 + SW4(row, gs)],
            &Bs[wave * 512 + r * 2048]);
    }
    __syncthreads();

    bf16x8 af[4], bf[4];
#pragma unroll
    for (int mt = 0; mt < 4; ++mt) {
      const int row = wr * 64 + mt * 16 + l15;
      af[mt] = *(const bf16x8*)&As[row * 32 + SW4(row, quad)];
    }
#pragma unroll
    for (int nt = 0; nt < 4; ++nt) {
      const int row = wc * 64 + nt * 16 + l15;
      bf[nt] = *(const bf16x8*)&Bs[row * 32 + SW4(row, quad)];
    }
#pragma unroll
    for (int mt = 0; mt < 4; ++mt)
#pragma unroll
      for (int nt = 0; nt < 4; ++nt)
        acc[mt][nt] = mfma16(af[mt], bf[nt], acc[mt][nt]);
  }

#pragma unroll
  for (int nt = 0; nt < 4; ++nt) {
    const int col = bn + wc * 64 + nt * 16 + l15;
    const float bi = bias[col];
    const float sc = (qscale && col < 1024) ? QSCALE : 1.0f;
#pragma unroll
    for (int mt = 0; mt < 4; ++mt) {
      const int row0 = bm + wr * 64 + mt * 16 + quad * 4;
#pragma unroll
      for (int reg = 0; reg < 4; ++reg) {
        const float v = (acc[mt][nt][reg] + bi) * sc;
        if (Cf) Cf[(size_t)(row0 + reg) * N + col] = v;
        else    Cb[(size_t)(row0 + reg) * N + col] = f2bf(v);
      }
    }
  }
}

// ---------------------------------------------------------------------------
// Fused masked-renorm attention: out = sum(e*M*V)/sum(e*M).
// R4 (VALU-thin): qb=64/block, swapped QK^T + TAU-permuted K rows (P stays in
// registers). New: exp2 (log2e pre-folded in GEMM1), mask via sbfe+and on exp
// bits, row-sum via MFMA-with-ones (replaces 16 adds/tile + epilogue shuffles),
// per-lane register-lookahead mask loads (Ms64 LDS + wave-0 serialization
// removed), asm-pinned zero/ones constants, hoisted staging pointers.
// ---------------------------------------------------------------------------
__global__ __launch_bounds__(256) void attn_kernel(
    const unsigned short* __restrict__ QK,      // [B*S][2048]
    const unsigned short* __restrict__ Vt,      // [B][H][HD][S]
    const unsigned long long* __restrict__ Mpk, // [B*S][S/64]
    unsigned short* __restrict__ ctx)           // [B*S][D]
{
  __shared__ unsigned short Ks[2][64 * 64];
  __shared__ unsigned short Vs[2][64 * 64];

  const int tid  = threadIdx.x;
  const int wave = tid >> 6, lane = tid & 63;
  const int quad = lane >> 4, l15 = lane & 15;
  const int b = blockIdx.z, h = blockIdx.y, qb = blockIdx.x * 64;
  const int gs = tid & 7;

  const unsigned short* Qbase = QK + (size_t)(b * S_ + qb) * 2048 + h * HD_;
  const unsigned short* Kbase = QK + (size_t)(b * S_) * 2048 + D_ + h * HD_;
  const unsigned short* Vbase = Vt + (size_t)((b * H_ + h) * HD_) * S_;
  // per-lane mask row: q-row = qb + wave*16 + l15 (4-way quad broadcast, L1-warm)
  const unsigned long long* Mrow =
      Mpk + (size_t)(b * S_ + qb + wave * 16 + l15) * (S_ / 64);

  // ---- stage Q (64x64, stride 64) into the Ks[0] region ----
  unsigned short* Qs = &Ks[0][0];
#pragma unroll
  for (int r = 0; r < 2; ++r) {
    const int row = (tid >> 3) + r * 32;
    gld16(Qbase + (size_t)row * 2048 + SW8(row, gs), Qs + wave * 512 + r * 2048);
  }
  unsigned long long mw_next = Mrow[0];      // mask lookahead (register)
  asm volatile("s_waitcnt vmcnt(0)" ::: "memory");
  __syncthreads();

  // loop-invariant Q fragments (rows wave*16..+15)
  bf16x8 qf[2];
#pragma unroll
  for (int c = 0; c < 2; ++c) {
    const int row = wave * 16 + l15;
    qf[c] = *(const bf16x8*)&Qs[row * 64 + SW8(row, c * 4 + quad)];
  }
  __syncthreads();   // all qf reads done before K tile-0 staging overwrites

  // ---- hoisted per-lane staging pointers (advance by constants per tile) ----
  const int rowd0 = tid >> 3, rowd1 = rowd0 + 32;
  const unsigned short* kp0 = Kbase + (size_t)TAU(rowd0) * 2048 + SW8(rowd0, gs);
  const unsigned short* kp1 = Kbase + (size_t)TAU(rowd1) * 2048 + SW8(rowd1, gs);
  const unsigned short* vp0 = Vbase + (size_t)rowd0 * S_ + SW8(rowd0, gs);
  const unsigned short* vp1 = Vbase + (size_t)rowd1 * S_ + SW8(rowd1, gs);

  // ---- stage tile 0 K (TAU-permuted rows) and V ----
  gld16(kp0, &Ks[0][wave * 512]);
  gld16(kp1, &Ks[0][wave * 512 + 2048]);
  gld16(vp0, &Vs[0][wave * 512]);
  gld16(vp1, &Vs[0][wave * 512 + 2048]);

  // opaque constants: zero acc-init + bf16 ones B-frag for MFMA row-sum
  floatx4 fz = (floatx4){0.f, 0.f, 0.f, 0.f};
  asm volatile("" : "+v"(fz));
  union { unsigned int w[4]; bf16x8 v; } onesU;
  onesU.w[0] = onesU.w[1] = onesU.w[2] = onesU.w[3] = 0x3F803F80u;  // bf16 1.0 x2
  bf16x8 ones = onesU.v;
  asm volatile("" : "+v"(ones));

  floatx4 accO[4];
  floatx4 accP = fz;                       // row-sum accumulator (MFMA-ones)
#pragma unroll
  for (int nt = 0; nt < 4; ++nt) accO[nt] = fz;

  const int q8 = quad * 8;

  for (int i = 0; i < 32; ++i) {
    const int cur = i & 1, nxt = cur ^ 1;
    asm volatile("s_waitcnt vmcnt(0)" ::: "memory");  // buf[cur] staged
    __syncthreads();  // all waves done with buf[nxt] (tile i-1)

    const unsigned long long mw = mw_next;

    if (i + 1 < 32) {  // prefetch tile i+1
      kp0 += 64 * 2048; kp1 += 64 * 2048; vp0 += 64; vp1 += 64;
      gld16(kp0, &Ks[nxt][wave * 512]);
      gld16(kp1, &Ks[nxt][wave * 512 + 2048]);
      gld16(vp0, &Vs[nxt][wave * 512]);
      gld16(vp1, &Vs[nxt][wave * 512 + 2048]);
      mw_next = Mrow[i + 1];
    }

    // S^T = K @ Q^T (swapped operands): lane l15 = q-row, quad/reg = token
    floatx4 sc[4];
    __builtin_amdgcn_s_setprio(1);
#pragma unroll
    for (int nt = 0; nt < 4; ++nt) {
      const int row = nt * 16 + l15;
      bf16x8 kf0 = *(const bf16x8*)&Ks[cur][row * 64 + SW8(row, quad)];
      bf16x8 kf1 = *(const bf16x8*)&Ks[cur][row * 64 + SW8(row, 4 + quad)];
      floatx4 z = mfma16(kf0, qf[0], fz);
      z = mfma16(kf1, qf[1], z);
      sc[nt] = z;
    }
    __builtin_amdgcn_s_setprio(0);

    // V fragments — independent of P, hoisted above the softmax
    bf16x8 vf0[4], vf1[4];
#pragma unroll
    for (int nt = 0; nt < 4; ++nt) {
      const int row = nt * 16 + l15;
      vf0[nt] = *(const bf16x8*)&Vs[cur][row * 64 + SW8(row, quad)];
      vf1[nt] = *(const bf16x8*)&Vs[cur][row * 64 + SW8(row, 4 + quad)];
    }

    // softmax: exp2 + sbfe/and mask, pack straight into PV A-frags
    const unsigned int w_lo = ((unsigned int)mw) >> q8;
    const unsigned int w_hi = ((unsigned int)(mw >> 32)) >> q8;
    bf16x8 pa0, pa1;
    {
      union { unsigned int w[4]; bf16x8 v; } A0, A1;
#pragma unroll
      for (int nt = 0; nt < 4; ++nt) {
        const unsigned int ws = (nt < 2) ? w_lo : w_hi;
        float p[4];
#pragma unroll
        for (int reg = 0; reg < 4; ++reg) {
          const int j = (nt & 1) * 4 + reg;      // bit 0..7 of ws
          const float e = EXP2(sc[nt][reg]);
          const int m = SBFE1(ws, j);             // 0 or -1
          p[reg] = __uint_as_float(__float_as_uint(e) & (unsigned int)m);
        }
        const unsigned int d0 = f2bf_pk(p[0], p[1]);
        const unsigned int d1 = f2bf_pk(p[2], p[3]);
        if (nt == 0)      { A0.w[0] = d0; A0.w[1] = d1; }
        else if (nt == 1) { A0.w[2] = d0; A0.w[3] = d1; }
        else if (nt == 2) { A1.w[0] = d0; A1.w[1] = d1; }
        else              { A1.w[2] = d0; A1.w[3] = d1; }
      }
      pa0 = A0.v; pa1 = A1.v;
    }

    // O += P @ V^T; row-sum += P @ ones (D-row = q = quad*4+reg)
    __builtin_amdgcn_s_setprio(1);
    accP = mfma16(pa0, ones, accP);
    accP = mfma16(pa1, ones, accP);
#pragma unroll
    for (int nt = 0; nt < 4; ++nt) {
      accO[nt] = mfma16(pa0, vf0[nt], accO[nt]);
      accO[nt] = mfma16(pa1, vf1[nt], accO[nt]);
    }
    __builtin_amdgcn_s_setprio(0);
  }

  // accP[reg] = full row-sum for q-row quad*4+reg (identical across l15)
  float Ppe[4];
#pragma unroll
  for (int reg = 0; reg < 4; ++reg)
    Ppe[reg] = 1.0f / (accP[reg] + 1e-30f);

#pragma unroll
  for (int nt = 0; nt < 4; ++nt)
#pragma unroll
    for (int reg = 0; reg < 4; ++reg) {
      const int row = wave * 16 + quad * 4 + reg;
      ctx[(size_t)(b * S_ + qb + row) * D_ + h * HD_ + nt * 16 + l15] =
          f2bf(accO[nt][reg] * Ppe[reg]);
    }
}

// ---------------------------------------------------------------------------
extern "C" void kernel_launch(void* const* d_in, const int* in_sizes, int n_in,
                              void* d_out, int out_size, void* d_ws, size_t ws_size,
                              hipStream_t stream) {
  const float* x     = (const float*)d_in[0];
  const float* V     = (const float*)d_in[1];
  const float* Mm    = (const float*)d_in[2];
  const float* w_in  = (const float*)d_in[3];
  const float* b_in  = (const float*)d_in[4];
  const float* w_out = (const float*)d_in[5];
  const float* b_out = (const float*)d_in[6];
  float* out = (float*)d_out;                  // fp32 (verified R5)

  // workspace layout (ushort units)
  unsigned short* qk  = (unsigned short*)d_ws;          // 8M   [4096][2048]
  unsigned short* vt  = qk  + (size_t)8 * 1024 * 1024;  // 4M   [B][H][HD][S]
  unsigned short* ctx = vt  + (size_t)4 * 1024 * 1024;  // 4M   [4096][1024]
  unsigned short* xb  = ctx + (size_t)4 * 1024 * 1024;  // 4M   bf16(x)
  unsigned short* wb  = xb  + (size_t)4 * 1024 * 1024;  // 2M   bf16(w_in[0:2048])
  unsigned short* wob = wb  + (size_t)2 * 1024 * 1024;  // 1M   bf16(out_w)
  unsigned long long* mpk = (unsigned long long*)(wob + (size_t)1024 * 1024);

  // 0) fused prep: converts + mask pack + V transpose (one dispatch)
  prep_kernel<<<6656, 256, 0, stream>>>(x, w_in, w_out, V, Mm,
                                        xb, wb, wob, vt, mpk);

  // 1) QK = x @ in_proj_w[0:2048]^T + b_in; Q cols pre-scaled by QSCALE
  gemm_abt<<<dim3(2048 / 128, (B_ * S_) / 128), 256, 0, stream>>>(
      xb, wb, b_in, qk, nullptr, B_ * S_, 2048, D_, 1);

  // 2) fused masked-renorm attention -> ctx (bf16)
  attn_kernel<<<dim3(S_ / 64, H_, B_), 256, 0, stream>>>(qk, vt, mpk, ctx);

  // 3) out = ctx @ out_w^T + out_b  (fp32 store to d_out)
  gemm_abt<<<dim3(D_ / 128, (B_ * S_) / 128), 256, 0, stream>>>(
      ctx, wob, b_out, nullptr, out, B_ * S_, D_, D_, 0);
}

// Round 5
// 245.192 us; speedup vs baseline: 1.0668x; 1.0668x over previous
//
#include <hip/hip_runtime.h>
#include <hip/hip_bf16.h>

// Problem constants: B=2, S=2048, D=1024, H=16, HD=64
#define B_  2
#define S_  2048
#define D_  1024
#define H_  16
#define HD_ 64

using bf16x8  = __attribute__((ext_vector_type(8))) __bf16;
using floatx4 = __attribute__((ext_vector_type(4))) float;
using intx4   = __attribute__((ext_vector_type(4))) int;

__device__ __forceinline__ unsigned short f2bf(float f) {
  union { float f; unsigned int i; } v; v.f = f;
  unsigned int r = v.i + 0x7fffu + ((v.i >> 16) & 1u);   // RNE
  return (unsigned short)(r >> 16);
}
// packed f32x2 -> bf16x2 (v_cvt_pk_bf16_f32 on gfx950; header fallback = same RNE)
__device__ __forceinline__ unsigned int f2bf_pk(float a, float b) {
  union { __hip_bfloat162 h2; unsigned int u; } c;
  c.h2 = __float22bfloat162_rn(make_float2(a, b));
  return c.u;   // low 16 = a, high 16 = b
}
__device__ __forceinline__ floatx4 mfma16(bf16x8 a, bf16x8 b, floatx4 c) {
  return __builtin_amdgcn_mfma_f32_16x16x32_bf16(a, b, c, 0, 0, 0);
}
// async global->LDS, 16B/lane; LDS dest = wave-uniform base + lane*16
__device__ __forceinline__ void gld16(const unsigned short* g, unsigned short* l) {
  __builtin_amdgcn_global_load_lds(
      (const __attribute__((address_space(1))) unsigned int*)g,
      (__attribute__((address_space(3))) unsigned int*)l, 16, 0, 0);
}
// native exp2 (scores are pre-scaled by log2e in GEMM1's qscale)
#if __has_builtin(__builtin_amdgcn_exp2f)
#define EXP2(x) __builtin_amdgcn_exp2f(x)
#else
#define EXP2(x) __expf((x) * 0.6931471805599453f)
#endif
// single-bit sign-extended extract: 0 or -1
#if __has_builtin(__builtin_amdgcn_sbfe)
#define SBFE1(x, o) __builtin_amdgcn_sbfe((int)(x), (o), 1)
#else
#define SBFE1(x, o) (((int)((x) << (31 - (o)))) >> 31)
#endif
// swizzles: ushort offset of 8-ushort group within a row
#define SW8(row, g) ((((g) ^ ((row) & 7)) * 8))          // 64-ushort rows
#define SW4(row, g) ((((g) ^ (((row) >> 1) & 3)) * 8))   // 32-ushort rows
// K-row permutation: LDS row r holds token TAU(r); bits (b5,b4,b3,b2,b1,b0) ->
// (b5,b3,b2,b4,b1,b0). Makes swapped-QK^T score layout == PV A-frag layout.
#define TAU(r) (((r) & 0x23) | (((r) & 0x08) << 1) | (((r) & 0x04) << 1) | (((r) & 0x10) >> 2))

// 0.125 (1/sqrt(HD)) * log2(e): folded so attn uses raw v_exp_f32 (exp2)
#define QSCALE 0.18033688011f

// ---------------------------------------------------------------------------
// prep: one dispatch doing all pre-passes (launch-overhead fusion).
// blocks [0,2048): cvt x | [2048,3072): cvt w_in[0:2048] | [3072,3584): cvt
// w_out | [3584,5632): mask->bitpack | [5632,6656): V transpose to [B][H][HD][S]
// ---------------------------------------------------------------------------
__global__ __launch_bounds__(256) void prep_kernel(
    const float* __restrict__ x, const float* __restrict__ w_in,
    const float* __restrict__ w_out, const float* __restrict__ V,
    const float* __restrict__ Mm,
    unsigned short* __restrict__ xb, unsigned short* __restrict__ wb,
    unsigned short* __restrict__ wob, unsigned short* __restrict__ vt,
    unsigned long long* __restrict__ mpk)
{
  __shared__ unsigned short tile[64 * 72];
  const int bid = blockIdx.x, tid = threadIdx.x;

  if (bid < 3584) {                       // bulk fp32->bf16 converts
    const float* src; unsigned short* dst; int base;
    if (bid < 2048)      { src = x;     dst = xb;  base = bid; }
    else if (bid < 3072) { src = w_in;  dst = wb;  base = bid - 2048; }
    else                 { src = w_out; dst = wob; base = bid - 3072; }
    const int i = (base * 256 + tid) * 8;
    float4 a = *(const float4*)(src + i);
    float4 b = *(const float4*)(src + i + 4);
    union { unsigned int w[4]; intx4 v; } o;
    o.w[0] = f2bf_pk(a.x, a.y); o.w[1] = f2bf_pk(a.z, a.w);
    o.w[2] = f2bf_pk(b.x, b.y); o.w[3] = f2bf_pk(b.z, b.w);
    *(intx4*)(dst + i) = o.v;
  } else if (bid < 5632) {                // mask bit-pack, 64 words/block
    const int wave = tid >> 6, lane = tid & 63;
    const int w0 = (bid - 3584) * 64 + wave * 16;
#pragma unroll 4
    for (int j = 0; j < 16; ++j) {
      float v = Mm[(size_t)(w0 + j) * 64 + lane];
      unsigned long long bl = __ballot(v != 0.0f);
      if (lane == 0) mpk[w0 + j] = bl;
    }
  } else {                                 // V transpose (b,h,64-token tile)
    const int idx = bid - 5632;
    const int t0 = (idx & 31) * 64, h = (idx >> 5) & 15, b = idx >> 9;
    const int sr = tid >> 3, sc = (tid & 7) * 8;
    const float* src = V + ((size_t)((b * S_ + t0) * H_ + h)) * HD_;
#pragma unroll
    for (int half = 0; half < 2; ++half) {
      const int r = sr + half * 32;
      float4 v0 = *(const float4*)&src[(size_t)r * (H_ * HD_) + sc];
      float4 v1 = *(const float4*)&src[(size_t)r * (H_ * HD_) + sc + 4];
      union { unsigned int w[4]; intx4 v; } p;
      p.w[0] = f2bf_pk(v0.x, v0.y); p.w[1] = f2bf_pk(v0.z, v0.w);
      p.w[2] = f2bf_pk(v1.x, v1.y); p.w[3] = f2bf_pk(v1.z, v1.w);
      *(intx4*)&tile[r * 72 + sc] = p.v;
    }
    __syncthreads();
    unsigned short* dst = vt + ((size_t)((b * H_ + h) * HD_)) * S_ + t0;
    union { unsigned short u[8]; intx4 v; } pack;
#pragma unroll
    for (int j = 0; j < 8; ++j) pack.u[j] = tile[(sc + j) * 72 + sr];
    *(intx4*)&dst[(size_t)sr * S_ + sc] = pack.v;
#pragma unroll
    for (int j = 0; j < 8; ++j) pack.u[j] = tile[(sc + j) * 72 + sr + 32];
    *(intx4*)&dst[(size_t)(sr + 32) * S_ + sc] = pack.v;
  }
}

// ---------------------------------------------------------------------------
// bf16 MFMA GEMM (m97-style): C = A @ Bm^T + bias. 128x128, BK=32,
// global_load_lds + XOR-swizzled LDS. qscale: cols<1024 *= QSCALE.
// ---------------------------------------------------------------------------
__global__ __launch_bounds__(256) void gemm_abt(
    const unsigned short* __restrict__ A,
    const unsigned short* __restrict__ Bm,
    const float* __restrict__ bias,
    unsigned short* __restrict__ Cb, float* __restrict__ Cf,
    int M, int N, int K, int qscale)
{
  __shared__ unsigned short As[128 * 32];
  __shared__ unsigned short Bs[128 * 32];

  const int tid  = threadIdx.x;
  const int wave = tid >> 6, lane = tid & 63;
  const int quad = lane >> 4, l15 = lane & 15;
  const int wr = wave >> 1, wc = wave & 1;
  const int bm = blockIdx.y * 128, bn = blockIdx.x * 128;
  const int srow = tid >> 2, gs = tid & 3;

  floatx4 acc[4][4];
#pragma unroll
  for (int mt = 0; mt < 4; ++mt)
#pragma unroll
    for (int nt = 0; nt < 4; ++nt)
      acc[mt][nt] = (floatx4){0.f, 0.f, 0.f, 0.f};

  for (int k0 = 0; k0 < K; k0 += 32) {
    __syncthreads();
#pragma unroll
    for (int r = 0; r < 2; ++r) {
      const int row = srow + r * 64;
      gld16(&A[(size_t)(bm + row) * K + k0 + SW4(row, gs)],
            &As[wave * 512 + r * 2048]);
      gld16(&Bm[(size_t)(bn + row) * K + k0 + SW4(row, gs)],
            &Bs[wave * 512 + r * 2048]);
    }
    __syncthreads();

    bf16x8 af[4], bf[4];
#pragma unroll
    for (int mt = 0; mt < 4; ++mt) {
      const int row = wr * 64 + mt * 16 + l15;
      af[mt] = *(const bf16x8*)&As[row * 32 + SW4(row, quad)];
    }
#pragma unroll
    for (int nt = 0; nt < 4; ++nt) {
      const int row = wc * 64 + nt * 16 + l15;
      bf[nt] = *(const bf16x8*)&Bs[row * 32 + SW4(row, quad)];
    }
#pragma unroll
    for (int mt = 0; mt < 4; ++mt)
#pragma unroll
      for (int nt = 0; nt < 4; ++nt)
        acc[mt][nt] = mfma16(af[mt], bf[nt], acc[mt][nt]);
  }

#pragma unroll
  for (int nt = 0; nt < 4; ++nt) {
    const int col = bn + wc * 64 + nt * 16 + l15;
    const float bi = bias[col];
    const float sc = (qscale && col < 1024) ? QSCALE : 1.0f;
#pragma unroll
    for (int mt = 0; mt < 4; ++mt) {
      const int row0 = bm + wr * 64 + mt * 16 + quad * 4;
#pragma unroll
      for (int reg = 0; reg < 4; ++reg) {
        const float v = (acc[mt][nt][reg] + bi) * sc;
        if (Cf) Cf[(size_t)(row0 + reg) * N + col] = v;
        else    Cb[(size_t)(row0 + reg) * N + col] = f2bf(v);
      }
    }
  }
}

// ---------------------------------------------------------------------------
// Fused masked-renorm attention: out = sum(e*M*V)/sum(e*M).
// R5 = R3 structure (qb=64/block, swapped QK^T + TAU-permuted K rows, P stays
// in registers, Ms64 LDS mask staging, shuffle epilogue, VGPR=64) + only the
// two pure-VALU-thinning changes from R4: exp2 (log2e folded into GEMM1's
// qscale) and sbfe+and masking (no VCC, 2 ops/elem). No pinned constants,
// no MFMA-ones, no per-lane mask loads (those crossed the 64-VGPR tier).
// ---------------------------------------------------------------------------
__global__ __launch_bounds__(256) void attn_kernel(
    const unsigned short* __restrict__ QK,      // [B*S][2048]
    const unsigned short* __restrict__ Vt,      // [B][H][HD][S]
    const unsigned long long* __restrict__ Mpk, // [B*S][S/64]
    unsigned short* __restrict__ ctx)           // [B*S][D]
{
  __shared__ unsigned short Ks[2][64 * 64];
  __shared__ unsigned short Vs[2][64 * 64];
  __shared__ unsigned long long Ms64[2][64];

  const int tid  = threadIdx.x;
  const int wave = tid >> 6, lane = tid & 63;
  const int quad = lane >> 4, l15 = lane & 15;
  const int b = blockIdx.z, h = blockIdx.y, qb = blockIdx.x * 64;
  const int gs = tid & 7;

  const unsigned short* Qbase = QK + (size_t)(b * S_ + qb) * 2048 + h * HD_;
  const unsigned short* Kbase = QK + (size_t)(b * S_) * 2048 + D_ + h * HD_;
  const unsigned short* Vbase = Vt + (size_t)((b * H_ + h) * HD_) * S_;
  const unsigned long long* Mbase = Mpk + (size_t)(b * S_ + qb) * (S_ / 64);

  // ---- stage Q (64x64, stride 64) into the Ks[0] region ----
  unsigned short* Qs = &Ks[0][0];
#pragma unroll
  for (int r = 0; r < 2; ++r) {
    const int row = (tid >> 3) + r * 32;
    gld16(Qbase + (size_t)row * 2048 + SW8(row, gs), Qs + wave * 512 + r * 2048);
  }
  if (tid < 64) Ms64[0][tid] = Mbase[(size_t)tid * (S_ / 64)];
  asm volatile("s_waitcnt vmcnt(0)" ::: "memory");
  __syncthreads();

  // loop-invariant Q fragments (rows wave*16..+15)
  bf16x8 qf[2];
#pragma unroll
  for (int c = 0; c < 2; ++c) {
    const int row = wave * 16 + l15;
    qf[c] = *(const bf16x8*)&Qs[row * 64 + SW8(row, c * 4 + quad)];
  }
  __syncthreads();   // all qf reads done before K tile-0 staging overwrites

  // ---- stage tile 0 K (TAU-permuted rows) and V ----
#pragma unroll
  for (int r = 0; r < 2; ++r) {
    const int rowd = (tid >> 3) + r * 32;
    const int tokK = TAU(rowd);
    gld16(Kbase + (size_t)tokK * 2048 + SW8(rowd, gs), &Ks[0][wave * 512 + r * 2048]);
    gld16(Vbase + (size_t)rowd * S_ + SW8(rowd, gs),   &Vs[0][wave * 512 + r * 2048]);
  }

  floatx4 accO[4];
  float Pp = 0.f;
#pragma unroll
  for (int nt = 0; nt < 4; ++nt)
    accO[nt] = (floatx4){0.f, 0.f, 0.f, 0.f};

  const int q8 = quad * 8;

  for (int i = 0; i < 32; ++i) {
    const int cur = i & 1, nxt = cur ^ 1;
    asm volatile("s_waitcnt vmcnt(0)" ::: "memory");  // buf[cur] staged
    __syncthreads();  // all waves done with buf[nxt] (tile i-1)

    if (i + 1 < 32) {  // prefetch tile i+1
      const int t1 = (i + 1) * 64;
#pragma unroll
      for (int r = 0; r < 2; ++r) {
        const int rowd = (tid >> 3) + r * 32;
        const int tokK = TAU(rowd);
        gld16(Kbase + (size_t)(t1 + tokK) * 2048 + SW8(rowd, gs),
              &Ks[nxt][wave * 512 + r * 2048]);
        gld16(Vbase + (size_t)rowd * S_ + t1 + SW8(rowd, gs),
              &Vs[nxt][wave * 512 + r * 2048]);
      }
      if (tid < 64)
        Ms64[nxt][tid] = Mbase[(size_t)tid * (S_ / 64) + i + 1];
    }

    // S^T = K @ Q^T (swapped operands): lane l15 = q-row, quad/reg = token
    floatx4 sc[4];
    __builtin_amdgcn_s_setprio(1);
#pragma unroll
    for (int nt = 0; nt < 4; ++nt) {
      const int row = nt * 16 + l15;
      bf16x8 kf0 = *(const bf16x8*)&Ks[cur][row * 64 + SW8(row, quad)];
      bf16x8 kf1 = *(const bf16x8*)&Ks[cur][row * 64 + SW8(row, 4 + quad)];
      floatx4 z = (floatx4){0.f, 0.f, 0.f, 0.f};
      z = mfma16(kf0, qf[0], z);
      z = mfma16(kf1, qf[1], z);
      sc[nt] = z;
    }
    __builtin_amdgcn_s_setprio(0);

    // mask word: one 64-bit word per q-row (lane-local q = l15), pre-shifted
    const unsigned long long mw = Ms64[cur][wave * 16 + l15];
    const unsigned int w_lo = ((unsigned int)mw) >> q8;
    const unsigned int w_hi = ((unsigned int)(mw >> 32)) >> q8;

    // V fragments — independent of P, hoisted above the softmax
    bf16x8 vf0[4], vf1[4];
#pragma unroll
    for (int nt = 0; nt < 4; ++nt) {
      const int row = nt * 16 + l15;
      vf0[nt] = *(const bf16x8*)&Vs[cur][row * 64 + SW8(row, quad)];
      vf1[nt] = *(const bf16x8*)&Vs[cur][row * 64 + SW8(row, 4 + quad)];
    }

    // softmax: exp2 + sbfe/and mask, pack straight into PV A-frags
    bf16x8 pa0, pa1;
    {
      union { unsigned int w[4]; bf16x8 v; } A0, A1;
#pragma unroll
      for (int nt = 0; nt < 4; ++nt) {
        const unsigned int ws = (nt < 2) ? w_lo : w_hi;
        float p[4];
#pragma unroll
        for (int reg = 0; reg < 4; ++reg) {
          const int j = (nt & 1) * 4 + reg;      // bit 0..7 of ws
          const float e = EXP2(sc[nt][reg]);
          const int m = SBFE1(ws, j);             // 0 or -1
          p[reg] = __uint_as_float(__float_as_uint(e) & (unsigned int)m);
        }
        Pp += (p[0] + p[1]) + (p[2] + p[3]);
        const unsigned int d0 = f2bf_pk(p[0], p[1]);
        const unsigned int d1 = f2bf_pk(p[2], p[3]);
        if (nt == 0)      { A0.w[0] = d0; A0.w[1] = d1; }
        else if (nt == 1) { A0.w[2] = d0; A0.w[3] = d1; }
        else if (nt == 2) { A1.w[0] = d0; A1.w[1] = d1; }
        else              { A1.w[2] = d0; A1.w[3] = d1; }
      }
      pa0 = A0.v; pa1 = A1.v;
    }

    // O += P @ V^T (P already in A-frag layout)
    __builtin_amdgcn_s_setprio(1);
#pragma unroll
    for (int nt = 0; nt < 4; ++nt) {
      accO[nt] = mfma16(pa0, vf0[nt], accO[nt]);
      accO[nt] = mfma16(pa1, vf1[nt], accO[nt]);
    }
    __builtin_amdgcn_s_setprio(0);
  }

  // Pp: lane (quad,l15) holds partial row-sum for q-row l15 over that quad's
  // tokens. Reduce over quads (lane^16, lane^32).
  Pp += __shfl_xor(Pp, 16);
  Pp += __shfl_xor(Pp, 32);
  Pp = 1.0f / (Pp + 1e-30f);
  // redistribute: epilogue needs inv-sum for q-row quad*4 + reg
  float Ppe[4];
#pragma unroll
  for (int reg = 0; reg < 4; ++reg)
    Ppe[reg] = __shfl(Pp, (quad << 4) | (quad * 4 + reg));

#pragma unroll
  for (int nt = 0; nt < 4; ++nt)
#pragma unroll
    for (int reg = 0; reg < 4; ++reg) {
      const int row = wave * 16 + quad * 4 + reg;
      ctx[(size_t)(b * S_ + qb + row) * D_ + h * HD_ + nt * 16 + l15] =
          f2bf(accO[nt][reg] * Ppe[reg]);
    }
}

// ---------------------------------------------------------------------------
extern "C" void kernel_launch(void* const* d_in, const int* in_sizes, int n_in,
                              void* d_out, int out_size, void* d_ws, size_t ws_size,
                              hipStream_t stream) {
  const float* x     = (const float*)d_in[0];
  const float* V     = (const float*)d_in[1];
  const float* Mm    = (const float*)d_in[2];
  const float* w_in  = (const float*)d_in[3];
  const float* b_in  = (const float*)d_in[4];
  const float* w_out = (const float*)d_in[5];
  const float* b_out = (const float*)d_in[6];
  float* out = (float*)d_out;                  // fp32 (verified R5)

  // workspace layout (ushort units)
  unsigned short* qk  = (unsigned short*)d_ws;          // 8M   [4096][2048]
  unsigned short* vt  = qk  + (size_t)8 * 1024 * 1024;  // 4M   [B][H][HD][S]
  unsigned short* ctx = vt  + (size_t)4 * 1024 * 1024;  // 4M   [4096][1024]
  unsigned short* xb  = ctx + (size_t)4 * 1024 * 1024;  // 4M   bf16(x)
  unsigned short* wb  = xb  + (size_t)4 * 1024 * 1024;  // 2M   bf16(w_in[0:2048])
  unsigned short* wob = wb  + (size_t)2 * 1024 * 1024;  // 1M   bf16(out_w)
  unsigned long long* mpk = (unsigned long long*)(wob + (size_t)1024 * 1024);

  // 0) fused prep: converts + mask pack + V transpose (one dispatch)
  prep_kernel<<<6656, 256, 0, stream>>>(x, w_in, w_out, V, Mm,
                                        xb, wb, wob, vt, mpk);

  // 1) QK = x @ in_proj_w[0:2048]^T + b_in; Q cols pre-scaled by QSCALE
  gemm_abt<<<dim3(2048 / 128, (B_ * S_) / 128), 256, 0, stream>>>(
      xb, wb, b_in, qk, nullptr, B_ * S_, 2048, D_, 1);

  // 2) fused masked-renorm attention -> ctx (bf16)
  attn_kernel<<<dim3(S_ / 64, H_, B_), 256, 0, stream>>>(qk, vt, mpk, ctx);

  // 3) out = ctx @ out_w^T + out_b  (fp32 store to d_out)
  gemm_abt<<<dim3(D_ / 128, (B_ * S_) / 128), 256, 0, stream>>>(
      ctx, wob, b_out, nullptr, out, B_ * S_, D_, D_, 0);
}

// Round 6
// 244.279 us; speedup vs baseline: 1.0708x; 1.0037x over previous
//
#include <hip/hip_runtime.h>
#include <hip/hip_bf16.h>

// Problem constants: B=2, S=2048, D=1024, H=16, HD=64
#define B_  2
#define S_  2048
#define D_  1024
#define H_  16
#define HD_ 64

using bf16x8  = __attribute__((ext_vector_type(8))) __bf16;
using floatx4 = __attribute__((ext_vector_type(4))) float;
using intx4   = __attribute__((ext_vector_type(4))) int;

__device__ __forceinline__ unsigned short f2bf(float f) {
  union { float f; unsigned int i; } v; v.f = f;
  unsigned int r = v.i + 0x7fffu + ((v.i >> 16) & 1u);   // RNE
  return (unsigned short)(r >> 16);
}
// packed f32x2 -> bf16x2. R6: direct v_cvt_pk_bf16_f32 (gfx950) — the HIP
// header's __float22bfloat162_rn lowers to a manual ~10-op RNE bit-sequence
// per pair (no builtin exists, T12/m240); this is 1 VALU op. low16=a, high16=b.
__device__ __forceinline__ unsigned int f2bf_pk(float a, float b) {
  unsigned int r;
  asm("v_cvt_pk_bf16_f32 %0, %1, %2" : "=v"(r) : "v"(a), "v"(b));
  return r;
}
__device__ __forceinline__ floatx4 mfma16(bf16x8 a, bf16x8 b, floatx4 c) {
  return __builtin_amdgcn_mfma_f32_16x16x32_bf16(a, b, c, 0, 0, 0);
}
// async global->LDS, 16B/lane; LDS dest = wave-uniform base + lane*16
__device__ __forceinline__ void gld16(const unsigned short* g, unsigned short* l) {
  __builtin_amdgcn_global_load_lds(
      (const __attribute__((address_space(1))) unsigned int*)g,
      (__attribute__((address_space(3))) unsigned int*)l, 16, 0, 0);
}
// native exp2 (scores are pre-scaled by log2e in GEMM1's qscale)
#if __has_builtin(__builtin_amdgcn_exp2f)
#define EXP2(x) __builtin_amdgcn_exp2f(x)
#else
#define EXP2(x) __expf((x) * 0.6931471805599453f)
#endif
// single-bit sign-extended extract: 0 or -1
#if __has_builtin(__builtin_amdgcn_sbfe)
#define SBFE1(x, o) __builtin_amdgcn_sbfe((int)(x), (o), 1)
#else
#define SBFE1(x, o) (((int)((x) << (31 - (o)))) >> 31)
#endif
// swizzles: ushort offset of 8-ushort group within a row
#define SW8(row, g) ((((g) ^ ((row) & 7)) * 8))          // 64-ushort rows
#define SW4(row, g) ((((g) ^ (((row) >> 1) & 3)) * 8))   // 32-ushort rows
// K-row permutation: LDS row r holds token TAU(r); bits (b5,b4,b3,b2,b1,b0) ->
// (b5,b3,b2,b4,b1,b0). Makes swapped-QK^T score layout == PV A-frag layout.
#define TAU(r) (((r) & 0x23) | (((r) & 0x08) << 1) | (((r) & 0x04) << 1) | (((r) & 0x10) >> 2))

// 0.125 (1/sqrt(HD)) * log2(e): folded so attn uses raw v_exp_f32 (exp2)
#define QSCALE 0.18033688011f

// ---------------------------------------------------------------------------
// prep: one dispatch doing all pre-passes (launch-overhead fusion).
// blocks [0,2048): cvt x | [2048,3072): cvt w_in[0:2048] | [3072,3584): cvt
// w_out | [3584,5632): mask->bitpack | [5632,6656): V transpose to [B][H][HD][S]
// ---------------------------------------------------------------------------
__global__ __launch_bounds__(256) void prep_kernel(
    const float* __restrict__ x, const float* __restrict__ w_in,
    const float* __restrict__ w_out, const float* __restrict__ V,
    const float* __restrict__ Mm,
    unsigned short* __restrict__ xb, unsigned short* __restrict__ wb,
    unsigned short* __restrict__ wob, unsigned short* __restrict__ vt,
    unsigned long long* __restrict__ mpk)
{
  __shared__ unsigned short tile[64 * 72];
  const int bid = blockIdx.x, tid = threadIdx.x;

  if (bid < 3584) {                       // bulk fp32->bf16 converts
    const float* src; unsigned short* dst; int base;
    if (bid < 2048)      { src = x;     dst = xb;  base = bid; }
    else if (bid < 3072) { src = w_in;  dst = wb;  base = bid - 2048; }
    else                 { src = w_out; dst = wob; base = bid - 3072; }
    const int i = (base * 256 + tid) * 8;
    float4 a = *(const float4*)(src + i);
    float4 b = *(const float4*)(src + i + 4);
    union { unsigned int w[4]; intx4 v; } o;
    o.w[0] = f2bf_pk(a.x, a.y); o.w[1] = f2bf_pk(a.z, a.w);
    o.w[2] = f2bf_pk(b.x, b.y); o.w[3] = f2bf_pk(b.z, b.w);
    *(intx4*)(dst + i) = o.v;
  } else if (bid < 5632) {                // mask bit-pack, 64 words/block
    const int wave = tid >> 6, lane = tid & 63;
    const int w0 = (bid - 3584) * 64 + wave * 16;
#pragma unroll 4
    for (int j = 0; j < 16; ++j) {
      float v = Mm[(size_t)(w0 + j) * 64 + lane];
      unsigned long long bl = __ballot(v != 0.0f);
      if (lane == 0) mpk[w0 + j] = bl;
    }
  } else {                                 // V transpose (b,h,64-token tile)
    const int idx = bid - 5632;
    const int t0 = (idx & 31) * 64, h = (idx >> 5) & 15, b = idx >> 9;
    const int sr = tid >> 3, sc = (tid & 7) * 8;
    const float* src = V + ((size_t)((b * S_ + t0) * H_ + h)) * HD_;
#pragma unroll
    for (int half = 0; half < 2; ++half) {
      const int r = sr + half * 32;
      float4 v0 = *(const float4*)&src[(size_t)r * (H_ * HD_) + sc];
      float4 v1 = *(const float4*)&src[(size_t)r * (H_ * HD_) + sc + 4];
      union { unsigned int w[4]; intx4 v; } p;
      p.w[0] = f2bf_pk(v0.x, v0.y); p.w[1] = f2bf_pk(v0.z, v0.w);
      p.w[2] = f2bf_pk(v1.x, v1.y); p.w[3] = f2bf_pk(v1.z, v1.w);
      *(intx4*)&tile[r * 72 + sc] = p.v;
    }
    __syncthreads();
    unsigned short* dst = vt + ((size_t)((b * H_ + h) * HD_)) * S_ + t0;
    union { unsigned short u[8]; intx4 v; } pack;
#pragma unroll
    for (int j = 0; j < 8; ++j) pack.u[j] = tile[(sc + j) * 72 + sr];
    *(intx4*)&dst[(size_t)sr * S_ + sc] = pack.v;
#pragma unroll
    for (int j = 0; j < 8; ++j) pack.u[j] = tile[(sc + j) * 72 + sr + 32];
    *(intx4*)&dst[(size_t)(sr + 32) * S_ + sc] = pack.v;
  }
}

// ---------------------------------------------------------------------------
// bf16 MFMA GEMM (m97-style): C = A @ Bm^T + bias. 128x128, BK=32,
// global_load_lds + XOR-swizzled LDS. qscale: cols<1024 *= QSCALE.
// ---------------------------------------------------------------------------
__global__ __launch_bounds__(256) void gemm_abt(
    const unsigned short* __restrict__ A,
    const unsigned short* __restrict__ Bm,
    const float* __restrict__ bias,
    unsigned short* __restrict__ Cb, float* __restrict__ Cf,
    int M, int N, int K, int qscale)
{
  __shared__ unsigned short As[128 * 32];
  __shared__ unsigned short Bs[128 * 32];

  const int tid  = threadIdx.x;
  const int wave = tid >> 6, lane = tid & 63;
  const int quad = lane >> 4, l15 = lane & 15;
  const int wr = wave >> 1, wc = wave & 1;
  const int bm = blockIdx.y * 128, bn = blockIdx.x * 128;
  const int srow = tid >> 2, gs = tid & 3;

  floatx4 acc[4][4];
#pragma unroll
  for (int mt = 0; mt < 4; ++mt)
#pragma unroll
    for (int nt = 0; nt < 4; ++nt)
      acc[mt][nt] = (floatx4){0.f, 0.f, 0.f, 0.f};

  for (int k0 = 0; k0 < K; k0 += 32) {
    __syncthreads();
#pragma unroll
    for (int r = 0; r < 2; ++r) {
      const int row = srow + r * 64;
      gld16(&A[(size_t)(bm + row) * K + k0 + SW4(row, gs)],
            &As[wave * 512 + r * 2048]);
      gld16(&Bm[(size_t)(bn + row) * K + k0 + SW4(row, gs)],
            &Bs[wave * 512 + r * 2048]);
    }
    __syncthreads();

    bf16x8 af[4], bf[4];
#pragma unroll
    for (int mt = 0; mt < 4; ++mt) {
      const int row = wr * 64 + mt * 16 + l15;
      af[mt] = *(const bf16x8*)&As[row * 32 + SW4(row, quad)];
    }
#pragma unroll
    for (int nt = 0; nt < 4; ++nt) {
      const int row = wc * 64 + nt * 16 + l15;
      bf[nt] = *(const bf16x8*)&Bs[row * 32 + SW4(row, quad)];
    }
#pragma unroll
    for (int mt = 0; mt < 4; ++mt)
#pragma unroll
      for (int nt = 0; nt < 4; ++nt)
        acc[mt][nt] = mfma16(af[mt], bf[nt], acc[mt][nt]);
  }

#pragma unroll
  for (int nt = 0; nt < 4; ++nt) {
    const int col = bn + wc * 64 + nt * 16 + l15;
    const float bi = bias[col];
    const float sc = (qscale && col < 1024) ? QSCALE : 1.0f;
#pragma unroll
    for (int mt = 0; mt < 4; ++mt) {
      const int row0 = bm + wr * 64 + mt * 16 + quad * 4;
#pragma unroll
      for (int reg = 0; reg < 4; ++reg) {
        const float v = (acc[mt][nt][reg] + bi) * sc;
        if (Cf) Cf[(size_t)(row0 + reg) * N + col] = v;
        else    Cb[(size_t)(row0 + reg) * N + col] = f2bf(v);
      }
    }
  }
}

// ---------------------------------------------------------------------------
// Fused masked-renorm attention: out = sum(e*M*V)/sum(e*M).
// R6 = R5 structure (qb=64/block, swapped QK^T + TAU-permuted K rows, P stays
// in registers, Ms64 LDS mask staging, shuffle epilogue, VGPR<=64) with
// f2bf_pk now a single v_cvt_pk_bf16_f32 (was header RNE sequence, ~10 ops
// per pair, 8 pairs/tile/wave -> suspected source of the VALUBusy gap).
// ---------------------------------------------------------------------------
__global__ __launch_bounds__(256) void attn_kernel(
    const unsigned short* __restrict__ QK,      // [B*S][2048]
    const unsigned short* __restrict__ Vt,      // [B][H][HD][S]
    const unsigned long long* __restrict__ Mpk, // [B*S][S/64]
    unsigned short* __restrict__ ctx)           // [B*S][D]
{
  __shared__ unsigned short Ks[2][64 * 64];
  __shared__ unsigned short Vs[2][64 * 64];
  __shared__ unsigned long long Ms64[2][64];

  const int tid  = threadIdx.x;
  const int wave = tid >> 6, lane = tid & 63;
  const int quad = lane >> 4, l15 = lane & 15;
  const int b = blockIdx.z, h = blockIdx.y, qb = blockIdx.x * 64;
  const int gs = tid & 7;

  const unsigned short* Qbase = QK + (size_t)(b * S_ + qb) * 2048 + h * HD_;
  const unsigned short* Kbase = QK + (size_t)(b * S_) * 2048 + D_ + h * HD_;
  const unsigned short* Vbase = Vt + (size_t)((b * H_ + h) * HD_) * S_;
  const unsigned long long* Mbase = Mpk + (size_t)(b * S_ + qb) * (S_ / 64);

  // ---- stage Q (64x64, stride 64) into the Ks[0] region ----
  unsigned short* Qs = &Ks[0][0];
#pragma unroll
  for (int r = 0; r < 2; ++r) {
    const int row = (tid >> 3) + r * 32;
    gld16(Qbase + (size_t)row * 2048 + SW8(row, gs), Qs + wave * 512 + r * 2048);
  }
  if (tid < 64) Ms64[0][tid] = Mbase[(size_t)tid * (S_ / 64)];
  asm volatile("s_waitcnt vmcnt(0)" ::: "memory");
  __syncthreads();

  // loop-invariant Q fragments (rows wave*16..+15)
  bf16x8 qf[2];
#pragma unroll
  for (int c = 0; c < 2; ++c) {
    const int row = wave * 16 + l15;
    qf[c] = *(const bf16x8*)&Qs[row * 64 + SW8(row, c * 4 + quad)];
  }
  __syncthreads();   // all qf reads done before K tile-0 staging overwrites

  // ---- stage tile 0 K (TAU-permuted rows) and V ----
#pragma unroll
  for (int r = 0; r < 2; ++r) {
    const int rowd = (tid >> 3) + r * 32;
    const int tokK = TAU(rowd);
    gld16(Kbase + (size_t)tokK * 2048 + SW8(rowd, gs), &Ks[0][wave * 512 + r * 2048]);
    gld16(Vbase + (size_t)rowd * S_ + SW8(rowd, gs),   &Vs[0][wave * 512 + r * 2048]);
  }

  floatx4 accO[4];
  float Pp = 0.f;
#pragma unroll
  for (int nt = 0; nt < 4; ++nt)
    accO[nt] = (floatx4){0.f, 0.f, 0.f, 0.f};

  const int q8 = quad * 8;

  for (int i = 0; i < 32; ++i) {
    const int cur = i & 1, nxt = cur ^ 1;
    asm volatile("s_waitcnt vmcnt(0)" ::: "memory");  // buf[cur] staged
    __syncthreads();  // all waves done with buf[nxt] (tile i-1)

    if (i + 1 < 32) {  // prefetch tile i+1
      const int t1 = (i + 1) * 64;
#pragma unroll
      for (int r = 0; r < 2; ++r) {
        const int rowd = (tid >> 3) + r * 32;
        const int tokK = TAU(rowd);
        gld16(Kbase + (size_t)(t1 + tokK) * 2048 + SW8(rowd, gs),
              &Ks[nxt][wave * 512 + r * 2048]);
        gld16(Vbase + (size_t)rowd * S_ + t1 + SW8(rowd, gs),
              &Vs[nxt][wave * 512 + r * 2048]);
      }
      if (tid < 64)
        Ms64[nxt][tid] = Mbase[(size_t)tid * (S_ / 64) + i + 1];
    }

    // S^T = K @ Q^T (swapped operands): lane l15 = q-row, quad/reg = token
    floatx4 sc[4];
    __builtin_amdgcn_s_setprio(1);
#pragma unroll
    for (int nt = 0; nt < 4; ++nt) {
      const int row = nt * 16 + l15;
      bf16x8 kf0 = *(const bf16x8*)&Ks[cur][row * 64 + SW8(row, quad)];
      bf16x8 kf1 = *(const bf16x8*)&Ks[cur][row * 64 + SW8(row, 4 + quad)];
      floatx4 z = (floatx4){0.f, 0.f, 0.f, 0.f};
      z = mfma16(kf0, qf[0], z);
      z = mfma16(kf1, qf[1], z);
      sc[nt] = z;
    }
    __builtin_amdgcn_s_setprio(0);

    // mask word: one 64-bit word per q-row (lane-local q = l15), pre-shifted
    const unsigned long long mw = Ms64[cur][wave * 16 + l15];
    const unsigned int w_lo = ((unsigned int)mw) >> q8;
    const unsigned int w_hi = ((unsigned int)(mw >> 32)) >> q8;

    // V fragments — independent of P, hoisted above the softmax
    bf16x8 vf0[4], vf1[4];
#pragma unroll
    for (int nt = 0; nt < 4; ++nt) {
      const int row = nt * 16 + l15;
      vf0[nt] = *(const bf16x8*)&Vs[cur][row * 64 + SW8(row, quad)];
      vf1[nt] = *(const bf16x8*)&Vs[cur][row * 64 + SW8(row, 4 + quad)];
    }

    // softmax: exp2 + sbfe/and mask, pack straight into PV A-frags
    bf16x8 pa0, pa1;
    {
      union { unsigned int w[4]; bf16x8 v; } A0, A1;
#pragma unroll
      for (int nt = 0; nt < 4; ++nt) {
        const unsigned int ws = (nt < 2) ? w_lo : w_hi;
        float p[4];
#pragma unroll
        for (int reg = 0; reg < 4; ++reg) {
          const int j = (nt & 1) * 4 + reg;      // bit 0..7 of ws
          const float e = EXP2(sc[nt][reg]);
          const int m = SBFE1(ws, j);             // 0 or -1
          p[reg] = __uint_as_float(__float_as_uint(e) & (unsigned int)m);
        }
        Pp += (p[0] + p[1]) + (p[2] + p[3]);
        const unsigned int d0 = f2bf_pk(p[0], p[1]);
        const unsigned int d1 = f2bf_pk(p[2], p[3]);
        if (nt == 0)      { A0.w[0] = d0; A0.w[1] = d1; }
        else if (nt == 1) { A0.w[2] = d0; A0.w[3] = d1; }
        else if (nt == 2) { A1.w[0] = d0; A1.w[1] = d1; }
        else              { A1.w[2] = d0; A1.w[3] = d1; }
      }
      pa0 = A0.v; pa1 = A1.v;
    }

    // O += P @ V^T (P already in A-frag layout)
    __builtin_amdgcn_s_setprio(1);
#pragma unroll
    for (int nt = 0; nt < 4; ++nt) {
      accO[nt] = mfma16(pa0, vf0[nt], accO[nt]);
      accO[nt] = mfma16(pa1, vf1[nt], accO[nt]);
    }
    __builtin_amdgcn_s_setprio(0);
  }

  // Pp: lane (quad,l15) holds partial row-sum for q-row l15 over that quad's
  // tokens. Reduce over quads (lane^16, lane^32).
  Pp += __shfl_xor(Pp, 16);
  Pp += __shfl_xor(Pp, 32);
  Pp = 1.0f / (Pp + 1e-30f);
  // redistribute: epilogue needs inv-sum for q-row quad*4 + reg
  float Ppe[4];
#pragma unroll
  for (int reg = 0; reg < 4; ++reg)
    Ppe[reg] = __shfl(Pp, (quad << 4) | (quad * 4 + reg));

#pragma unroll
  for (int nt = 0; nt < 4; ++nt)
#pragma unroll
    for (int reg = 0; reg < 4; ++reg) {
      const int row = wave * 16 + quad * 4 + reg;
      ctx[(size_t)(b * S_ + qb + row) * D_ + h * HD_ + nt * 16 + l15] =
          f2bf(accO[nt][reg] * Ppe[reg]);
    }
}

// ---------------------------------------------------------------------------
extern "C" void kernel_launch(void* const* d_in, const int* in_sizes, int n_in,
                              void* d_out, int out_size, void* d_ws, size_t ws_size,
                              hipStream_t stream) {
  const float* x     = (const float*)d_in[0];
  const float* V     = (const float*)d_in[1];
  const float* Mm    = (const float*)d_in[2];
  const float* w_in  = (const float*)d_in[3];
  const float* b_in  = (const float*)d_in[4];
  const float* w_out = (const float*)d_in[5];
  const float* b_out = (const float*)d_in[6];
  float* out = (float*)d_out;                  // fp32 (verified R5)

  // workspace layout (ushort units)
  unsigned short* qk  = (unsigned short*)d_ws;          // 8M   [4096][2048]
  unsigned short* vt  = qk  + (size_t)8 * 1024 * 1024;  // 4M   [B][H][HD][S]
  unsigned short* ctx = vt  + (size_t)4 * 1024 * 1024;  // 4M   [4096][1024]
  unsigned short* xb  = ctx + (size_t)4 * 1024 * 1024;  // 4M   bf16(x)
  unsigned short* wb  = xb  + (size_t)4 * 1024 * 1024;  // 2M   bf16(w_in[0:2048])
  unsigned short* wob = wb  + (size_t)2 * 1024 * 1024;  // 1M   bf16(out_w)
  unsigned long long* mpk = (unsigned long long*)(wob + (size_t)1024 * 1024);

  // 0) fused prep: converts + mask pack + V transpose (one dispatch)
  prep_kernel<<<6656, 256, 0, stream>>>(x, w_in, w_out, V, Mm,
                                        xb, wb, wob, vt, mpk);

  // 1) QK = x @ in_proj_w[0:2048]^T + b_in; Q cols pre-scaled by QSCALE
  gemm_abt<<<dim3(2048 / 128, (B_ * S_) / 128), 256, 0, stream>>>(
      xb, wb, b_in, qk, nullptr, B_ * S_, 2048, D_, 1);

  // 2) fused masked-renorm attention -> ctx (bf16)
  attn_kernel<<<dim3(S_ / 64, H_, B_), 256, 0, stream>>>(qk, vt, mpk, ctx);

  // 3) out = ctx @ out_w^T + out_b  (fp32 store to d_out)
  gemm_abt<<<dim3(D_ / 128, (B_ * S_) / 128), 256, 0, stream>>>(
      ctx, wob, b_out, nullptr, out, B_ * S_, D_, D_, 0);
}

// Round 7
// 240.334 us; speedup vs baseline: 1.0884x; 1.0164x over previous
//
#include <hip/hip_runtime.h>
#include <hip/hip_bf16.h>

// Problem constants: B=2, S=2048, D=1024, H=16, HD=64
#define B_  2
#define S_  2048
#define D_  1024
#define H_  16
#define HD_ 64

using bf16x8  = __attribute__((ext_vector_type(8))) __bf16;
using floatx4 = __attribute__((ext_vector_type(4))) float;
using intx4   = __attribute__((ext_vector_type(4))) int;

__device__ __forceinline__ unsigned short f2bf(float f) {
  union { float f; unsigned int i; } v; v.f = f;
  unsigned int r = v.i + 0x7fffu + ((v.i >> 16) & 1u);   // RNE
  return (unsigned short)(r >> 16);
}
// packed f32x2 -> bf16x2: single v_cvt_pk_bf16_f32 (header fallback is ~10 ops)
__device__ __forceinline__ unsigned int f2bf_pk(float a, float b) {
  unsigned int r;
  asm("v_cvt_pk_bf16_f32 %0, %1, %2" : "=v"(r) : "v"(a), "v"(b));
  return r;
}
__device__ __forceinline__ floatx4 mfma16(bf16x8 a, bf16x8 b, floatx4 c) {
  return __builtin_amdgcn_mfma_f32_16x16x32_bf16(a, b, c, 0, 0, 0);
}
// async global->LDS, 16B/lane; LDS dest = wave-uniform base + lane*16
__device__ __forceinline__ void gld16(const unsigned short* g, unsigned short* l) {
  __builtin_amdgcn_global_load_lds(
      (const __attribute__((address_space(1))) unsigned int*)g,
      (__attribute__((address_space(3))) unsigned int*)l, 16, 0, 0);
}
// native exp2 (scores are pre-scaled by log2e in GEMM1's qscale)
#if __has_builtin(__builtin_amdgcn_exp2f)
#define EXP2(x) __builtin_amdgcn_exp2f(x)
#else
#define EXP2(x) __expf((x) * 0.6931471805599453f)
#endif
// single-bit sign-extended extract: 0 or -1
#if __has_builtin(__builtin_amdgcn_sbfe)
#define SBFE1(x, o) __builtin_amdgcn_sbfe((int)(x), (o), 1)
#else
#define SBFE1(x, o) (((int)((x) << (31 - (o)))) >> 31)
#endif
// swizzles: ushort offset of 8-ushort group within a row
#define SW8(row, g) ((((g) ^ ((row) & 7)) * 8))          // 64-ushort rows
#define SW4(row, g) ((((g) ^ (((row) >> 1) & 3)) * 8))   // 32-ushort rows
// K-row permutation: LDS row r holds token TAU(r); bits (b5,b4,b3,b2,b1,b0) ->
// (b5,b3,b2,b4,b1,b0). Makes swapped-QK^T score layout == PV A-frag layout.
#define TAU(r) (((r) & 0x23) | (((r) & 0x08) << 1) | (((r) & 0x04) << 1) | (((r) & 0x10) >> 2))

// 0.125 (1/sqrt(HD)) * log2(e): folded so attn uses raw v_exp_f32 (exp2)
#define QSCALE 0.18033688011f

// ---------------------------------------------------------------------------
// prep: one dispatch doing all pre-passes (launch-overhead fusion).
// blocks [0,2048): cvt x | [2048,3072): cvt w_in[0:2048] | [3072,3584): cvt
// w_out | [3584,5632): mask->bitpack | [5632,6656): V transpose to [B][H][HD][S]
// ---------------------------------------------------------------------------
__global__ __launch_bounds__(256) void prep_kernel(
    const float* __restrict__ x, const float* __restrict__ w_in,
    const float* __restrict__ w_out, const float* __restrict__ V,
    const float* __restrict__ Mm,
    unsigned short* __restrict__ xb, unsigned short* __restrict__ wb,
    unsigned short* __restrict__ wob, unsigned short* __restrict__ vt,
    unsigned long long* __restrict__ mpk)
{
  __shared__ unsigned short tile[64 * 72];
  const int bid = blockIdx.x, tid = threadIdx.x;

  if (bid < 3584) {                       // bulk fp32->bf16 converts
    const float* src; unsigned short* dst; int base;
    if (bid < 2048)      { src = x;     dst = xb;  base = bid; }
    else if (bid < 3072) { src = w_in;  dst = wb;  base = bid - 2048; }
    else                 { src = w_out; dst = wob; base = bid - 3072; }
    const int i = (base * 256 + tid) * 8;
    float4 a = *(const float4*)(src + i);
    float4 b = *(const float4*)(src + i + 4);
    union { unsigned int w[4]; intx4 v; } o;
    o.w[0] = f2bf_pk(a.x, a.y); o.w[1] = f2bf_pk(a.z, a.w);
    o.w[2] = f2bf_pk(b.x, b.y); o.w[3] = f2bf_pk(b.z, b.w);
    *(intx4*)(dst + i) = o.v;
  } else if (bid < 5632) {                // mask bit-pack, 64 words/block
    const int wave = tid >> 6, lane = tid & 63;
    const int w0 = (bid - 3584) * 64 + wave * 16;
#pragma unroll 4
    for (int j = 0; j < 16; ++j) {
      float v = Mm[(size_t)(w0 + j) * 64 + lane];
      unsigned long long bl = __ballot(v != 0.0f);
      if (lane == 0) mpk[w0 + j] = bl;
    }
  } else {                                 // V transpose (b,h,64-token tile)
    const int idx = bid - 5632;
    const int t0 = (idx & 31) * 64, h = (idx >> 5) & 15, b = idx >> 9;
    const int sr = tid >> 3, sc = (tid & 7) * 8;
    const float* src = V + ((size_t)((b * S_ + t0) * H_ + h)) * HD_;
#pragma unroll
    for (int half = 0; half < 2; ++half) {
      const int r = sr + half * 32;
      float4 v0 = *(const float4*)&src[(size_t)r * (H_ * HD_) + sc];
      float4 v1 = *(const float4*)&src[(size_t)r * (H_ * HD_) + sc + 4];
      union { unsigned int w[4]; intx4 v; } p;
      p.w[0] = f2bf_pk(v0.x, v0.y); p.w[1] = f2bf_pk(v0.z, v0.w);
      p.w[2] = f2bf_pk(v1.x, v1.y); p.w[3] = f2bf_pk(v1.z, v1.w);
      *(intx4*)&tile[r * 72 + sc] = p.v;
    }
    __syncthreads();
    unsigned short* dst = vt + ((size_t)((b * H_ + h) * HD_)) * S_ + t0;
    union { unsigned short u[8]; intx4 v; } pack;
#pragma unroll
    for (int j = 0; j < 8; ++j) pack.u[j] = tile[(sc + j) * 72 + sr];
    *(intx4*)&dst[(size_t)sr * S_ + sc] = pack.v;
#pragma unroll
    for (int j = 0; j < 8; ++j) pack.u[j] = tile[(sc + j) * 72 + sr + 32];
    *(intx4*)&dst[(size_t)(sr + 32) * S_ + sc] = pack.v;
  }
}

// ---------------------------------------------------------------------------
// bf16 MFMA GEMM, templated tile: C = A @ Bm^T + bias. BK=32, wave grid 2x2,
// wave-tile (BM/2)x(BN/2). R7: smaller tiles for occupancy at these shapes
// (gemm1 64x128 -> 1024 blocks = 4/CU; gemm2 64x64 -> 1024 blocks = 4/CU).
// qscale: cols<1024 *= QSCALE.
// ---------------------------------------------------------------------------
template<int BM, int BN>
__global__ __launch_bounds__(256) void gemm_tile(
    const unsigned short* __restrict__ A,
    const unsigned short* __restrict__ Bm,
    const float* __restrict__ bias,
    unsigned short* __restrict__ Cb, float* __restrict__ Cf,
    int N, int K, int qscale)
{
  constexpr int MT = BM / 32;    // 16x16 frags per wave in M (wave-tile BM/2)
  constexpr int NT = BN / 32;    // frags per wave in N (wave-tile BN/2)
  __shared__ unsigned short As[BM * 32];
  __shared__ unsigned short Bs[BN * 32];

  const int tid  = threadIdx.x;
  const int wave = tid >> 6, lane = tid & 63;
  const int quad = lane >> 4, l15 = lane & 15;
  const int wr = wave >> 1, wc = wave & 1;
  const int bm = blockIdx.y * BM, bn = blockIdx.x * BN;
  const int srow = tid >> 2, gs = tid & 3;

  floatx4 acc[MT][NT];
#pragma unroll
  for (int mt = 0; mt < MT; ++mt)
#pragma unroll
    for (int nt = 0; nt < NT; ++nt)
      acc[mt][nt] = (floatx4){0.f, 0.f, 0.f, 0.f};

  for (int k0 = 0; k0 < K; k0 += 32) {
    __syncthreads();
#pragma unroll
    for (int r = 0; r < BM / 64; ++r) {
      const int row = srow + r * 64;
      gld16(&A[(size_t)(bm + row) * K + k0 + SW4(row, gs)],
            &As[wave * 512 + r * 2048]);
    }
#pragma unroll
    for (int r = 0; r < BN / 64; ++r) {
      const int row = srow + r * 64;
      gld16(&Bm[(size_t)(bn + row) * K + k0 + SW4(row, gs)],
            &Bs[wave * 512 + r * 2048]);
    }
    __syncthreads();

    bf16x8 af[MT], bf[NT];
#pragma unroll
    for (int mt = 0; mt < MT; ++mt) {
      const int row = wr * (BM / 2) + mt * 16 + l15;
      af[mt] = *(const bf16x8*)&As[row * 32 + SW4(row, quad)];
    }
#pragma unroll
    for (int nt = 0; nt < NT; ++nt) {
      const int row = wc * (BN / 2) + nt * 16 + l15;
      bf[nt] = *(const bf16x8*)&Bs[row * 32 + SW4(row, quad)];
    }
#pragma unroll
    for (int mt = 0; mt < MT; ++mt)
#pragma unroll
      for (int nt = 0; nt < NT; ++nt)
        acc[mt][nt] = mfma16(af[mt], bf[nt], acc[mt][nt]);
  }

#pragma unroll
  for (int nt = 0; nt < NT; ++nt) {
    const int col = bn + wc * (BN / 2) + nt * 16 + l15;
    const float bi = bias[col];
    const float sc = (qscale && col < 1024) ? QSCALE : 1.0f;
#pragma unroll
    for (int mt = 0; mt < MT; ++mt) {
      const int row0 = bm + wr * (BM / 2) + mt * 16 + quad * 4;
#pragma unroll
      for (int reg = 0; reg < 4; ++reg) {
        const float v = (acc[mt][nt][reg] + bi) * sc;
        if (Cf) Cf[(size_t)(row0 + reg) * N + col] = v;
        else    Cb[(size_t)(row0 + reg) * N + col] = f2bf(v);
      }
    }
  }
}

// ---------------------------------------------------------------------------
// Fused masked-renorm attention: out = sum(e*M*V)/sum(e*M).
// R7 = R6 byte-identical (qb=64/block, swapped QK^T + TAU-permuted K rows,
// P in registers, Ms64 LDS mask staging, exp2 + sbfe/and mask, asm cvt_pk,
// shuffle epilogue, VGPR=56).
// ---------------------------------------------------------------------------
__global__ __launch_bounds__(256) void attn_kernel(
    const unsigned short* __restrict__ QK,      // [B*S][2048]
    const unsigned short* __restrict__ Vt,      // [B][H][HD][S]
    const unsigned long long* __restrict__ Mpk, // [B*S][S/64]
    unsigned short* __restrict__ ctx)           // [B*S][D]
{
  __shared__ unsigned short Ks[2][64 * 64];
  __shared__ unsigned short Vs[2][64 * 64];
  __shared__ unsigned long long Ms64[2][64];

  const int tid  = threadIdx.x;
  const int wave = tid >> 6, lane = tid & 63;
  const int quad = lane >> 4, l15 = lane & 15;
  const int b = blockIdx.z, h = blockIdx.y, qb = blockIdx.x * 64;
  const int gs = tid & 7;

  const unsigned short* Qbase = QK + (size_t)(b * S_ + qb) * 2048 + h * HD_;
  const unsigned short* Kbase = QK + (size_t)(b * S_) * 2048 + D_ + h * HD_;
  const unsigned short* Vbase = Vt + (size_t)((b * H_ + h) * HD_) * S_;
  const unsigned long long* Mbase = Mpk + (size_t)(b * S_ + qb) * (S_ / 64);

  // ---- stage Q (64x64, stride 64) into the Ks[0] region ----
  unsigned short* Qs = &Ks[0][0];
#pragma unroll
  for (int r = 0; r < 2; ++r) {
    const int row = (tid >> 3) + r * 32;
    gld16(Qbase + (size_t)row * 2048 + SW8(row, gs), Qs + wave * 512 + r * 2048);
  }
  if (tid < 64) Ms64[0][tid] = Mbase[(size_t)tid * (S_ / 64)];
  asm volatile("s_waitcnt vmcnt(0)" ::: "memory");
  __syncthreads();

  // loop-invariant Q fragments (rows wave*16..+15)
  bf16x8 qf[2];
#pragma unroll
  for (int c = 0; c < 2; ++c) {
    const int row = wave * 16 + l15;
    qf[c] = *(const bf16x8*)&Qs[row * 64 + SW8(row, c * 4 + quad)];
  }
  __syncthreads();   // all qf reads done before K tile-0 staging overwrites

  // ---- stage tile 0 K (TAU-permuted rows) and V ----
#pragma unroll
  for (int r = 0; r < 2; ++r) {
    const int rowd = (tid >> 3) + r * 32;
    const int tokK = TAU(rowd);
    gld16(Kbase + (size_t)tokK * 2048 + SW8(rowd, gs), &Ks[0][wave * 512 + r * 2048]);
    gld16(Vbase + (size_t)rowd * S_ + SW8(rowd, gs),   &Vs[0][wave * 512 + r * 2048]);
  }

  floatx4 accO[4];
  float Pp = 0.f;
#pragma unroll
  for (int nt = 0; nt < 4; ++nt)
    accO[nt] = (floatx4){0.f, 0.f, 0.f, 0.f};

  const int q8 = quad * 8;

  for (int i = 0; i < 32; ++i) {
    const int cur = i & 1, nxt = cur ^ 1;
    asm volatile("s_waitcnt vmcnt(0)" ::: "memory");  // buf[cur] staged
    __syncthreads();  // all waves done with buf[nxt] (tile i-1)

    if (i + 1 < 32) {  // prefetch tile i+1
      const int t1 = (i + 1) * 64;
#pragma unroll
      for (int r = 0; r < 2; ++r) {
        const int rowd = (tid >> 3) + r * 32;
        const int tokK = TAU(rowd);
        gld16(Kbase + (size_t)(t1 + tokK) * 2048 + SW8(rowd, gs),
              &Ks[nxt][wave * 512 + r * 2048]);
        gld16(Vbase + (size_t)rowd * S_ + t1 + SW8(rowd, gs),
              &Vs[nxt][wave * 512 + r * 2048]);
      }
      if (tid < 64)
        Ms64[nxt][tid] = Mbase[(size_t)tid * (S_ / 64) + i + 1];
    }

    // S^T = K @ Q^T (swapped operands): lane l15 = q-row, quad/reg = token
    floatx4 sc[4];
    __builtin_amdgcn_s_setprio(1);
#pragma unroll
    for (int nt = 0; nt < 4; ++nt) {
      const int row = nt * 16 + l15;
      bf16x8 kf0 = *(const bf16x8*)&Ks[cur][row * 64 + SW8(row, quad)];
      bf16x8 kf1 = *(const bf16x8*)&Ks[cur][row * 64 + SW8(row, 4 + quad)];
      floatx4 z = (floatx4){0.f, 0.f, 0.f, 0.f};
      z = mfma16(kf0, qf[0], z);
      z = mfma16(kf1, qf[1], z);
      sc[nt] = z;
    }
    __builtin_amdgcn_s_setprio(0);

    // mask word: one 64-bit word per q-row (lane-local q = l15), pre-shifted
    const unsigned long long mw = Ms64[cur][wave * 16 + l15];
    const unsigned int w_lo = ((unsigned int)mw) >> q8;
    const unsigned int w_hi = ((unsigned int)(mw >> 32)) >> q8;

    // V fragments — independent of P, hoisted above the softmax
    bf16x8 vf0[4], vf1[4];
#pragma unroll
    for (int nt = 0; nt < 4; ++nt) {
      const int row = nt * 16 + l15;
      vf0[nt] = *(const bf16x8*)&Vs[cur][row * 64 + SW8(row, quad)];
      vf1[nt] = *(const bf16x8*)&Vs[cur][row * 64 + SW8(row, 4 + quad)];
    }

    // softmax: exp2 + sbfe/and mask, pack straight into PV A-frags
    bf16x8 pa0, pa1;
    {
      union { unsigned int w[4]; bf16x8 v; } A0, A1;
#pragma unroll
      for (int nt = 0; nt < 4; ++nt) {
        const unsigned int ws = (nt < 2) ? w_lo : w_hi;
        float p[4];
#pragma unroll
        for (int reg = 0; reg < 4; ++reg) {
          const int j = (nt & 1) * 4 + reg;      // bit 0..7 of ws
          const float e = EXP2(sc[nt][reg]);
          const int m = SBFE1(ws, j);             // 0 or -1
          p[reg] = __uint_as_float(__float_as_uint(e) & (unsigned int)m);
        }
        Pp += (p[0] + p[1]) + (p[2] + p[3]);
        const unsigned int d0 = f2bf_pk(p[0], p[1]);
        const unsigned int d1 = f2bf_pk(p[2], p[3]);
        if (nt == 0)      { A0.w[0] = d0; A0.w[1] = d1; }
        else if (nt == 1) { A0.w[2] = d0; A0.w[3] = d1; }
        else if (nt == 2) { A1.w[0] = d0; A1.w[1] = d1; }
        else              { A1.w[2] = d0; A1.w[3] = d1; }
      }
      pa0 = A0.v; pa1 = A1.v;
    }

    // O += P @ V^T (P already in A-frag layout)
    __builtin_amdgcn_s_setprio(1);
#pragma unroll
    for (int nt = 0; nt < 4; ++nt) {
      accO[nt] = mfma16(pa0, vf0[nt], accO[nt]);
      accO[nt] = mfma16(pa1, vf1[nt], accO[nt]);
    }
    __builtin_amdgcn_s_setprio(0);
  }

  // Pp: lane (quad,l15) holds partial row-sum for q-row l15 over that quad's
  // tokens. Reduce over quads (lane^16, lane^32).
  Pp += __shfl_xor(Pp, 16);
  Pp += __shfl_xor(Pp, 32);
  Pp = 1.0f / (Pp + 1e-30f);
  // redistribute: epilogue needs inv-sum for q-row quad*4 + reg
  float Ppe[4];
#pragma unroll
  for (int reg = 0; reg < 4; ++reg)
    Ppe[reg] = __shfl(Pp, (quad << 4) | (quad * 4 + reg));

#pragma unroll
  for (int nt = 0; nt < 4; ++nt)
#pragma unroll
    for (int reg = 0; reg < 4; ++reg) {
      const int row = wave * 16 + quad * 4 + reg;
      ctx[(size_t)(b * S_ + qb + row) * D_ + h * HD_ + nt * 16 + l15] =
          f2bf(accO[nt][reg] * Ppe[reg]);
    }
}

// ---------------------------------------------------------------------------
extern "C" void kernel_launch(void* const* d_in, const int* in_sizes, int n_in,
                              void* d_out, int out_size, void* d_ws, size_t ws_size,
                              hipStream_t stream) {
  const float* x     = (const float*)d_in[0];
  const float* V     = (const float*)d_in[1];
  const float* Mm    = (const float*)d_in[2];
  const float* w_in  = (const float*)d_in[3];
  const float* b_in  = (const float*)d_in[4];
  const float* w_out = (const float*)d_in[5];
  const float* b_out = (const float*)d_in[6];
  float* out = (float*)d_out;                  // fp32 (verified R5)

  // workspace layout (ushort units)
  unsigned short* qk  = (unsigned short*)d_ws;          // 8M   [4096][2048]
  unsigned short* vt  = qk  + (size_t)8 * 1024 * 1024;  // 4M   [B][H][HD][S]
  unsigned short* ctx = vt  + (size_t)4 * 1024 * 1024;  // 4M   [4096][1024]
  unsigned short* xb  = ctx + (size_t)4 * 1024 * 1024;  // 4M   bf16(x)
  unsigned short* wb  = xb  + (size_t)4 * 1024 * 1024;  // 2M   bf16(w_in[0:2048])
  unsigned short* wob = wb  + (size_t)2 * 1024 * 1024;  // 1M   bf16(out_w)
  unsigned long long* mpk = (unsigned long long*)(wob + (size_t)1024 * 1024);

  // 0) fused prep: converts + mask pack + V transpose (one dispatch)
  prep_kernel<<<6656, 256, 0, stream>>>(x, w_in, w_out, V, Mm,
                                        xb, wb, wob, vt, mpk);

  // 1) QK = x @ in_proj_w[0:2048]^T + b_in; Q cols pre-scaled by QSCALE
  //    64x128 tile -> 1024 blocks = 4 blocks/CU (was 512 = 2/CU)
  gemm_tile<64, 128><<<dim3(2048 / 128, (B_ * S_) / 64), 256, 0, stream>>>(
      xb, wb, b_in, qk, nullptr, 2048, D_, 1);

  // 2) fused masked-renorm attention -> ctx (bf16)
  attn_kernel<<<dim3(S_ / 64, H_, B_), 256, 0, stream>>>(qk, vt, mpk, ctx);

  // 3) out = ctx @ out_w^T + out_b  (fp32 store to d_out)
  //    64x64 tile -> 1024 blocks = 4 blocks/CU (was 256 = 1/CU)
  gemm_tile<64, 64><<<dim3(D_ / 64, (B_ * S_) / 64), 256, 0, stream>>>(
      ctx, wob, b_out, nullptr, out, D_, D_, 0);
}

// Round 8
// 229.093 us; speedup vs baseline: 1.1418x; 1.0491x over previous
//
#include <hip/hip_runtime.h>
#include <hip/hip_bf16.h>

// Problem constants: B=2, S=2048, D=1024, H=16, HD=64
#define B_  2
#define S_  2048
#define D_  1024
#define H_  16
#define HD_ 64

using bf16x8  = __attribute__((ext_vector_type(8))) __bf16;
using floatx4 = __attribute__((ext_vector_type(4))) float;
using intx4   = __attribute__((ext_vector_type(4))) int;

__device__ __forceinline__ unsigned short f2bf(float f) {
  union { float f; unsigned int i; } v; v.f = f;
  unsigned int r = v.i + 0x7fffu + ((v.i >> 16) & 1u);   // RNE
  return (unsigned short)(r >> 16);
}
// packed f32x2 -> bf16x2: single v_cvt_pk_bf16_f32 (header fallback is ~10 ops)
__device__ __forceinline__ unsigned int f2bf_pk(float a, float b) {
  unsigned int r;
  asm("v_cvt_pk_bf16_f32 %0, %1, %2" : "=v"(r) : "v"(a), "v"(b));
  return r;
}
__device__ __forceinline__ floatx4 mfma16(bf16x8 a, bf16x8 b, floatx4 c) {
  return __builtin_amdgcn_mfma_f32_16x16x32_bf16(a, b, c, 0, 0, 0);
}
// async global->LDS, 16B/lane; LDS dest = wave-uniform base + lane*16
__device__ __forceinline__ void gld16(const unsigned short* g, unsigned short* l) {
  __builtin_amdgcn_global_load_lds(
      (const __attribute__((address_space(1))) unsigned int*)g,
      (__attribute__((address_space(3))) unsigned int*)l, 16, 0, 0);
}
// native exp2 (scores are pre-scaled by log2e in GEMM1's qscale)
#if __has_builtin(__builtin_amdgcn_exp2f)
#define EXP2(x) __builtin_amdgcn_exp2f(x)
#else
#define EXP2(x) __expf((x) * 0.6931471805599453f)
#endif
// single-bit sign-extended extract: 0 or -1
#if __has_builtin(__builtin_amdgcn_sbfe)
#define SBFE1(x, o) __builtin_amdgcn_sbfe((int)(x), (o), 1)
#else
#define SBFE1(x, o) (((int)((x) << (31 - (o)))) >> 31)
#endif
// swizzles: ushort offset of 8-ushort group within a row
#define SW8(row, g) ((((g) ^ ((row) & 7)) * 8))          // 64-ushort rows
#define SW4(row, g) ((((g) ^ (((row) >> 1) & 3)) * 8))   // 32-ushort rows
// K-row permutation: LDS row r holds token TAU(r); bits (b5,b4,b3,b2,b1,b0) ->
// (b5,b3,b2,b4,b1,b0). Makes swapped-QK^T score layout == PV A-frag layout.
#define TAU(r) (((r) & 0x23) | (((r) & 0x08) << 1) | (((r) & 0x04) << 1) | (((r) & 0x10) >> 2))

// 0.125 (1/sqrt(HD)) * log2(e): folded so attn uses raw v_exp_f32 (exp2)
#define QSCALE 0.18033688011f

// ---------------------------------------------------------------------------
// prep: one dispatch doing all pre-passes (launch-overhead fusion).
// blocks [0,2048): cvt x | [2048,3072): cvt w_in[0:2048] | [3072,3584): cvt
// w_out | [3584,5632): mask->bitpack | [5632,6656): V transpose to [B][H][HD][S]
// ---------------------------------------------------------------------------
__global__ __launch_bounds__(256) void prep_kernel(
    const float* __restrict__ x, const float* __restrict__ w_in,
    const float* __restrict__ w_out, const float* __restrict__ V,
    const float* __restrict__ Mm,
    unsigned short* __restrict__ xb, unsigned short* __restrict__ wb,
    unsigned short* __restrict__ wob, unsigned short* __restrict__ vt,
    unsigned long long* __restrict__ mpk)
{
  __shared__ unsigned short tile[64 * 72];
  const int bid = blockIdx.x, tid = threadIdx.x;

  if (bid < 3584) {                       // bulk fp32->bf16 converts
    const float* src; unsigned short* dst; int base;
    if (bid < 2048)      { src = x;     dst = xb;  base = bid; }
    else if (bid < 3072) { src = w_in;  dst = wb;  base = bid - 2048; }
    else                 { src = w_out; dst = wob; base = bid - 3072; }
    const int i = (base * 256 + tid) * 8;
    float4 a = *(const float4*)(src + i);
    float4 b = *(const float4*)(src + i + 4);
    union { unsigned int w[4]; intx4 v; } o;
    o.w[0] = f2bf_pk(a.x, a.y); o.w[1] = f2bf_pk(a.z, a.w);
    o.w[2] = f2bf_pk(b.x, b.y); o.w[3] = f2bf_pk(b.z, b.w);
    *(intx4*)(dst + i) = o.v;
  } else if (bid < 5632) {                // mask bit-pack, 64 words/block
    const int wave = tid >> 6, lane = tid & 63;
    const int w0 = (bid - 3584) * 64 + wave * 16;
#pragma unroll 4
    for (int j = 0; j < 16; ++j) {
      float v = Mm[(size_t)(w0 + j) * 64 + lane];
      unsigned long long bl = __ballot(v != 0.0f);
      if (lane == 0) mpk[w0 + j] = bl;
    }
  } else {                                 // V transpose (b,h,64-token tile)
    const int idx = bid - 5632;
    const int t0 = (idx & 31) * 64, h = (idx >> 5) & 15, b = idx >> 9;
    const int sr = tid >> 3, sc = (tid & 7) * 8;
    const float* src = V + ((size_t)((b * S_ + t0) * H_ + h)) * HD_;
#pragma unroll
    for (int half = 0; half < 2; ++half) {
      const int r = sr + half * 32;
      float4 v0 = *(const float4*)&src[(size_t)r * (H_ * HD_) + sc];
      float4 v1 = *(const float4*)&src[(size_t)r * (H_ * HD_) + sc + 4];
      union { unsigned int w[4]; intx4 v; } p;
      p.w[0] = f2bf_pk(v0.x, v0.y); p.w[1] = f2bf_pk(v0.z, v0.w);
      p.w[2] = f2bf_pk(v1.x, v1.y); p.w[3] = f2bf_pk(v1.z, v1.w);
      *(intx4*)&tile[r * 72 + sc] = p.v;
    }
    __syncthreads();
    unsigned short* dst = vt + ((size_t)((b * H_ + h) * HD_)) * S_ + t0;
    union { unsigned short u[8]; intx4 v; } pack;
#pragma unroll
    for (int j = 0; j < 8; ++j) pack.u[j] = tile[(sc + j) * 72 + sr];
    *(intx4*)&dst[(size_t)sr * S_ + sc] = pack.v;
#pragma unroll
    for (int j = 0; j < 8; ++j) pack.u[j] = tile[(sc + j) * 72 + sr + 32];
    *(intx4*)&dst[(size_t)(sr + 32) * S_ + sc] = pack.v;
  }
}

// ---------------------------------------------------------------------------
// bf16 MFMA GEMM, templated tile: C = A @ Bm^T + bias. BK=32, wave grid 2x2,
// wave-tile (BM/2)x(BN/2). R8: double-buffered staging (attn-style) — stage
// k+1 is issued AFTER the barrier and drained one full K-step later, hiding
// the HBM/L2 latency under the current step's ds_read+MFMA. (R7 exposed the
// full staging latency every K-step: stage -> vmcnt(0)+barrier -> compute.)
// qscale: cols<1024 *= QSCALE.
// ---------------------------------------------------------------------------
template<int BM, int BN>
__global__ __launch_bounds__(256) void gemm_tile(
    const unsigned short* __restrict__ A,
    const unsigned short* __restrict__ Bm,
    const float* __restrict__ bias,
    unsigned short* __restrict__ Cb, float* __restrict__ Cf,
    int N, int K, int qscale)
{
  constexpr int MT = BM / 32;    // 16x16 frags per wave in M (wave-tile BM/2)
  constexpr int NT = BN / 32;    // frags per wave in N (wave-tile BN/2)
  __shared__ unsigned short As[2][BM * 32];
  __shared__ unsigned short Bs[2][BN * 32];

  const int tid  = threadIdx.x;
  const int wave = tid >> 6, lane = tid & 63;
  const int quad = lane >> 4, l15 = lane & 15;
  const int wr = wave >> 1, wc = wave & 1;
  const int bm = blockIdx.y * BM, bn = blockIdx.x * BN;
  const int srow = tid >> 2, gs = tid & 3;

  auto stage = [&](int buf, int k0) {
#pragma unroll
    for (int r = 0; r < BM / 64; ++r) {
      const int row = srow + r * 64;
      gld16(&A[(size_t)(bm + row) * K + k0 + SW4(row, gs)],
            &As[buf][wave * 512 + r * 2048]);
    }
#pragma unroll
    for (int r = 0; r < BN / 64; ++r) {
      const int row = srow + r * 64;
      gld16(&Bm[(size_t)(bn + row) * K + k0 + SW4(row, gs)],
            &Bs[buf][wave * 512 + r * 2048]);
    }
  };

  floatx4 acc[MT][NT];
#pragma unroll
  for (int mt = 0; mt < MT; ++mt)
#pragma unroll
    for (int nt = 0; nt < NT; ++nt)
      acc[mt][nt] = (floatx4){0.f, 0.f, 0.f, 0.f};

  stage(0, 0);                       // prologue: tile 0 in flight

  const int KSTEPS = K / 32;
  for (int ks = 0; ks < KSTEPS; ++ks) {
    const int cur = ks & 1, nxt = cur ^ 1;
    asm volatile("s_waitcnt vmcnt(0)" ::: "memory");  // buf[cur] staged
    __syncthreads();  // all waves done reading buf[nxt] (step ks-1)

    if (ks + 1 < KSTEPS) stage(nxt, (ks + 1) * 32);   // prefetch step ks+1

    bf16x8 af[MT], bf[NT];
#pragma unroll
    for (int mt = 0; mt < MT; ++mt) {
      const int row = wr * (BM / 2) + mt * 16 + l15;
      af[mt] = *(const bf16x8*)&As[cur][row * 32 + SW4(row, quad)];
    }
#pragma unroll
    for (int nt = 0; nt < NT; ++nt) {
      const int row = wc * (BN / 2) + nt * 16 + l15;
      bf[nt] = *(const bf16x8*)&Bs[cur][row * 32 + SW4(row, quad)];
    }
    __builtin_amdgcn_s_setprio(1);
#pragma unroll
    for (int mt = 0; mt < MT; ++mt)
#pragma unroll
      for (int nt = 0; nt < NT; ++nt)
        acc[mt][nt] = mfma16(af[mt], bf[nt], acc[mt][nt]);
    __builtin_amdgcn_s_setprio(0);
  }

#pragma unroll
  for (int nt = 0; nt < NT; ++nt) {
    const int col = bn + wc * (BN / 2) + nt * 16 + l15;
    const float bi = bias[col];
    const float sc = (qscale && col < 1024) ? QSCALE : 1.0f;
#pragma unroll
    for (int mt = 0; mt < MT; ++mt) {
      const int row0 = bm + wr * (BM / 2) + mt * 16 + quad * 4;
#pragma unroll
      for (int reg = 0; reg < 4; ++reg) {
        const float v = (acc[mt][nt][reg] + bi) * sc;
        if (Cf) Cf[(size_t)(row0 + reg) * N + col] = v;
        else    Cb[(size_t)(row0 + reg) * N + col] = f2bf(v);
      }
    }
  }
}

// ---------------------------------------------------------------------------
// Fused masked-renorm attention: out = sum(e*M*V)/sum(e*M).
// R8 = R6/R7 byte-identical (qb=64/block, swapped QK^T + TAU-permuted K rows,
// P in registers, Ms64 LDS mask staging, exp2 + sbfe/and mask, asm cvt_pk,
// shuffle epilogue, VGPR=56).
// ---------------------------------------------------------------------------
__global__ __launch_bounds__(256) void attn_kernel(
    const unsigned short* __restrict__ QK,      // [B*S][2048]
    const unsigned short* __restrict__ Vt,      // [B][H][HD][S]
    const unsigned long long* __restrict__ Mpk, // [B*S][S/64]
    unsigned short* __restrict__ ctx)           // [B*S][D]
{
  __shared__ unsigned short Ks[2][64 * 64];
  __shared__ unsigned short Vs[2][64 * 64];
  __shared__ unsigned long long Ms64[2][64];

  const int tid  = threadIdx.x;
  const int wave = tid >> 6, lane = tid & 63;
  const int quad = lane >> 4, l15 = lane & 15;
  const int b = blockIdx.z, h = blockIdx.y, qb = blockIdx.x * 64;
  const int gs = tid & 7;

  const unsigned short* Qbase = QK + (size_t)(b * S_ + qb) * 2048 + h * HD_;
  const unsigned short* Kbase = QK + (size_t)(b * S_) * 2048 + D_ + h * HD_;
  const unsigned short* Vbase = Vt + (size_t)((b * H_ + h) * HD_) * S_;
  const unsigned long long* Mbase = Mpk + (size_t)(b * S_ + qb) * (S_ / 64);

  // ---- stage Q (64x64, stride 64) into the Ks[0] region ----
  unsigned short* Qs = &Ks[0][0];
#pragma unroll
  for (int r = 0; r < 2; ++r) {
    const int row = (tid >> 3) + r * 32;
    gld16(Qbase + (size_t)row * 2048 + SW8(row, gs), Qs + wave * 512 + r * 2048);
  }
  if (tid < 64) Ms64[0][tid] = Mbase[(size_t)tid * (S_ / 64)];
  asm volatile("s_waitcnt vmcnt(0)" ::: "memory");
  __syncthreads();

  // loop-invariant Q fragments (rows wave*16..+15)
  bf16x8 qf[2];
#pragma unroll
  for (int c = 0; c < 2; ++c) {
    const int row = wave * 16 + l15;
    qf[c] = *(const bf16x8*)&Qs[row * 64 + SW8(row, c * 4 + quad)];
  }
  __syncthreads();   // all qf reads done before K tile-0 staging overwrites

  // ---- stage tile 0 K (TAU-permuted rows) and V ----
#pragma unroll
  for (int r = 0; r < 2; ++r) {
    const int rowd = (tid >> 3) + r * 32;
    const int tokK = TAU(rowd);
    gld16(Kbase + (size_t)tokK * 2048 + SW8(rowd, gs), &Ks[0][wave * 512 + r * 2048]);
    gld16(Vbase + (size_t)rowd * S_ + SW8(rowd, gs),   &Vs[0][wave * 512 + r * 2048]);
  }

  floatx4 accO[4];
  float Pp = 0.f;
#pragma unroll
  for (int nt = 0; nt < 4; ++nt)
    accO[nt] = (floatx4){0.f, 0.f, 0.f, 0.f};

  const int q8 = quad * 8;

  for (int i = 0; i < 32; ++i) {
    const int cur = i & 1, nxt = cur ^ 1;
    asm volatile("s_waitcnt vmcnt(0)" ::: "memory");  // buf[cur] staged
    __syncthreads();  // all waves done with buf[nxt] (tile i-1)

    if (i + 1 < 32) {  // prefetch tile i+1
      const int t1 = (i + 1) * 64;
#pragma unroll
      for (int r = 0; r < 2; ++r) {
        const int rowd = (tid >> 3) + r * 32;
        const int tokK = TAU(rowd);
        gld16(Kbase + (size_t)(t1 + tokK) * 2048 + SW8(rowd, gs),
              &Ks[nxt][wave * 512 + r * 2048]);
        gld16(Vbase + (size_t)rowd * S_ + t1 + SW8(rowd, gs),
              &Vs[nxt][wave * 512 + r * 2048]);
      }
      if (tid < 64)
        Ms64[nxt][tid] = Mbase[(size_t)tid * (S_ / 64) + i + 1];
    }

    // S^T = K @ Q^T (swapped operands): lane l15 = q-row, quad/reg = token
    floatx4 sc[4];
    __builtin_amdgcn_s_setprio(1);
#pragma unroll
    for (int nt = 0; nt < 4; ++nt) {
      const int row = nt * 16 + l15;
      bf16x8 kf0 = *(const bf16x8*)&Ks[cur][row * 64 + SW8(row, quad)];
      bf16x8 kf1 = *(const bf16x8*)&Ks[cur][row * 64 + SW8(row, 4 + quad)];
      floatx4 z = (floatx4){0.f, 0.f, 0.f, 0.f};
      z = mfma16(kf0, qf[0], z);
      z = mfma16(kf1, qf[1], z);
      sc[nt] = z;
    }
    __builtin_amdgcn_s_setprio(0);

    // mask word: one 64-bit word per q-row (lane-local q = l15), pre-shifted
    const unsigned long long mw = Ms64[cur][wave * 16 + l15];
    const unsigned int w_lo = ((unsigned int)mw) >> q8;
    const unsigned int w_hi = ((unsigned int)(mw >> 32)) >> q8;

    // V fragments — independent of P, hoisted above the softmax
    bf16x8 vf0[4], vf1[4];
#pragma unroll
    for (int nt = 0; nt < 4; ++nt) {
      const int row = nt * 16 + l15;
      vf0[nt] = *(const bf16x8*)&Vs[cur][row * 64 + SW8(row, quad)];
      vf1[nt] = *(const bf16x8*)&Vs[cur][row * 64 + SW8(row, 4 + quad)];
    }

    // softmax: exp2 + sbfe/and mask, pack straight into PV A-frags
    bf16x8 pa0, pa1;
    {
      union { unsigned int w[4]; bf16x8 v; } A0, A1;
#pragma unroll
      for (int nt = 0; nt < 4; ++nt) {
        const unsigned int ws = (nt < 2) ? w_lo : w_hi;
        float p[4];
#pragma unroll
        for (int reg = 0; reg < 4; ++reg) {
          const int j = (nt & 1) * 4 + reg;      // bit 0..7 of ws
          const float e = EXP2(sc[nt][reg]);
          const int m = SBFE1(ws, j);             // 0 or -1
          p[reg] = __uint_as_float(__float_as_uint(e) & (unsigned int)m);
        }
        Pp += (p[0] + p[1]) + (p[2] + p[3]);
        const unsigned int d0 = f2bf_pk(p[0], p[1]);
        const unsigned int d1 = f2bf_pk(p[2], p[3]);
        if (nt == 0)      { A0.w[0] = d0; A0.w[1] = d1; }
        else if (nt == 1) { A0.w[2] = d0; A0.w[3] = d1; }
        else if (nt == 2) { A1.w[0] = d0; A1.w[1] = d1; }
        else              { A1.w[2] = d0; A1.w[3] = d1; }
      }
      pa0 = A0.v; pa1 = A1.v;
    }

    // O += P @ V^T (P already in A-frag layout)
    __builtin_amdgcn_s_setprio(1);
#pragma unroll
    for (int nt = 0; nt < 4; ++nt) {
      accO[nt] = mfma16(pa0, vf0[nt], accO[nt]);
      accO[nt] = mfma16(pa1, vf1[nt], accO[nt]);
    }
    __builtin_amdgcn_s_setprio(0);
  }

  // Pp: lane (quad,l15) holds partial row-sum for q-row l15 over that quad's
  // tokens. Reduce over quads (lane^16, lane^32).
  Pp += __shfl_xor(Pp, 16);
  Pp += __shfl_xor(Pp, 32);
  Pp = 1.0f / (Pp + 1e-30f);
  // redistribute: epilogue needs inv-sum for q-row quad*4 + reg
  float Ppe[4];
#pragma unroll
  for (int reg = 0; reg < 4; ++reg)
    Ppe[reg] = __shfl(Pp, (quad << 4) | (quad * 4 + reg));

#pragma unroll
  for (int nt = 0; nt < 4; ++nt)
#pragma unroll
    for (int reg = 0; reg < 4; ++reg) {
      const int row = wave * 16 + quad * 4 + reg;
      ctx[(size_t)(b * S_ + qb + row) * D_ + h * HD_ + nt * 16 + l15] =
          f2bf(accO[nt][reg] * Ppe[reg]);
    }
}

// ---------------------------------------------------------------------------
extern "C" void kernel_launch(void* const* d_in, const int* in_sizes, int n_in,
                              void* d_out, int out_size, void* d_ws, size_t ws_size,
                              hipStream_t stream) {
  const float* x     = (const float*)d_in[0];
  const float* V     = (const float*)d_in[1];
  const float* Mm    = (const float*)d_in[2];
  const float* w_in  = (const float*)d_in[3];
  const float* b_in  = (const float*)d_in[4];
  const float* w_out = (const float*)d_in[5];
  const float* b_out = (const float*)d_in[6];
  float* out = (float*)d_out;                  // fp32 (verified R5)

  // workspace layout (ushort units)
  unsigned short* qk  = (unsigned short*)d_ws;          // 8M   [4096][2048]
  unsigned short* vt  = qk  + (size_t)8 * 1024 * 1024;  // 4M   [B][H][HD][S]
  unsigned short* ctx = vt  + (size_t)4 * 1024 * 1024;  // 4M   [4096][1024]
  unsigned short* xb  = ctx + (size_t)4 * 1024 * 1024;  // 4M   bf16(x)
  unsigned short* wb  = xb  + (size_t)4 * 1024 * 1024;  // 2M   bf16(w_in[0:2048])
  unsigned short* wob = wb  + (size_t)2 * 1024 * 1024;  // 1M   bf16(out_w)
  unsigned long long* mpk = (unsigned long long*)(wob + (size_t)1024 * 1024);

  // 0) fused prep: converts + mask pack + V transpose (one dispatch)
  prep_kernel<<<6656, 256, 0, stream>>>(x, w_in, w_out, V, Mm,
                                        xb, wb, wob, vt, mpk);

  // 1) QK = x @ in_proj_w[0:2048]^T + b_in; Q cols pre-scaled by QSCALE
  //    64x128 tile, double-buffered staging; 1024 blocks = 4/CU
  gemm_tile<64, 128><<<dim3(2048 / 128, (B_ * S_) / 64), 256, 0, stream>>>(
      xb, wb, b_in, qk, nullptr, 2048, D_, 1);

  // 2) fused masked-renorm attention -> ctx (bf16)
  attn_kernel<<<dim3(S_ / 64, H_, B_), 256, 0, stream>>>(qk, vt, mpk, ctx);

  // 3) out = ctx @ out_w^T + out_b  (fp32 store to d_out)
  //    64x64 tile, double-buffered staging; 1024 blocks = 4/CU
  gemm_tile<64, 64><<<dim3(D_ / 64, (B_ * S_) / 64), 256, 0, stream>>>(
      ctx, wob, b_out, nullptr, out, D_, D_, 0);
}

// Round 9
// 227.690 us; speedup vs baseline: 1.1488x; 1.0062x over previous
//
#include <hip/hip_runtime.h>
#include <hip/hip_bf16.h>

// Problem constants: B=2, S=2048, D=1024, H=16, HD=64
#define B_  2
#define S_  2048
#define D_  1024
#define H_  16
#define HD_ 64

using bf16x8  = __attribute__((ext_vector_type(8))) __bf16;
using floatx4 = __attribute__((ext_vector_type(4))) float;
using intx4   = __attribute__((ext_vector_type(4))) int;

__device__ __forceinline__ unsigned short f2bf(float f) {
  union { float f; unsigned int i; } v; v.f = f;
  unsigned int r = v.i + 0x7fffu + ((v.i >> 16) & 1u);   // RNE
  return (unsigned short)(r >> 16);
}
// packed f32x2 -> bf16x2: single v_cvt_pk_bf16_f32 (header fallback is ~10 ops)
__device__ __forceinline__ unsigned int f2bf_pk(float a, float b) {
  unsigned int r;
  asm("v_cvt_pk_bf16_f32 %0, %1, %2" : "=v"(r) : "v"(a), "v"(b));
  return r;
}
__device__ __forceinline__ floatx4 mfma16(bf16x8 a, bf16x8 b, floatx4 c) {
  return __builtin_amdgcn_mfma_f32_16x16x32_bf16(a, b, c, 0, 0, 0);
}
// async global->LDS, 16B/lane; LDS dest = wave-uniform base + lane*16
__device__ __forceinline__ void gld16(const unsigned short* g, unsigned short* l) {
  __builtin_amdgcn_global_load_lds(
      (const __attribute__((address_space(1))) unsigned int*)g,
      (__attribute__((address_space(3))) unsigned int*)l, 16, 0, 0);
}
// native exp2 (scores are pre-scaled by log2e in GEMM1's qscale)
#if __has_builtin(__builtin_amdgcn_exp2f)
#define EXP2(x) __builtin_amdgcn_exp2f(x)
#else
#define EXP2(x) __expf((x) * 0.6931471805599453f)
#endif
// single-bit sign-extended extract: 0 or -1
#if __has_builtin(__builtin_amdgcn_sbfe)
#define SBFE1(x, o) __builtin_amdgcn_sbfe((int)(x), (o), 1)
#else
#define SBFE1(x, o) (((int)((x) << (31 - (o)))) >> 31)
#endif
// swizzles: ushort offset of 8-ushort group within a row
#define SW8(row, g) ((((g) ^ ((row) & 7)) * 8))          // 64-ushort rows
#define SW4(row, g) ((((g) ^ (((row) >> 1) & 3)) * 8))   // 32-ushort rows
// K-row permutation: LDS row r holds token TAU(r); bits (b5,b4,b3,b2,b1,b0) ->
// (b5,b3,b2,b4,b1,b0). Makes swapped-QK^T score layout == PV A-frag layout.
#define TAU(r) (((r) & 0x23) | (((r) & 0x08) << 1) | (((r) & 0x04) << 1) | (((r) & 0x10) >> 2))

// 0.125 (1/sqrt(HD)) * log2(e): folded so attn uses raw v_exp_f32 (exp2)
#define QSCALE 0.18033688011f

// ---------------------------------------------------------------------------
// prep: one dispatch doing all pre-passes (launch-overhead fusion).
// blocks [0,2048): cvt x | [2048,3072): cvt w_in[0:2048] | [3072,3584): cvt
// w_out | [3584,5632): mask->bitpack | [5632,6656): V transpose to [B][H][HD][S]
// (streaming, no inter-block reuse -> no XCD swizzle; T1 is null here)
// ---------------------------------------------------------------------------
__global__ __launch_bounds__(256) void prep_kernel(
    const float* __restrict__ x, const float* __restrict__ w_in,
    const float* __restrict__ w_out, const float* __restrict__ V,
    const float* __restrict__ Mm,
    unsigned short* __restrict__ xb, unsigned short* __restrict__ wb,
    unsigned short* __restrict__ wob, unsigned short* __restrict__ vt,
    unsigned long long* __restrict__ mpk)
{
  __shared__ unsigned short tile[64 * 72];
  const int bid = blockIdx.x, tid = threadIdx.x;

  if (bid < 3584) {                       // bulk fp32->bf16 converts
    const float* src; unsigned short* dst; int base;
    if (bid < 2048)      { src = x;     dst = xb;  base = bid; }
    else if (bid < 3072) { src = w_in;  dst = wb;  base = bid - 2048; }
    else                 { src = w_out; dst = wob; base = bid - 3072; }
    const int i = (base * 256 + tid) * 8;
    float4 a = *(const float4*)(src + i);
    float4 b = *(const float4*)(src + i + 4);
    union { unsigned int w[4]; intx4 v; } o;
    o.w[0] = f2bf_pk(a.x, a.y); o.w[1] = f2bf_pk(a.z, a.w);
    o.w[2] = f2bf_pk(b.x, b.y); o.w[3] = f2bf_pk(b.z, b.w);
    *(intx4*)(dst + i) = o.v;
  } else if (bid < 5632) {                // mask bit-pack, 64 words/block
    const int wave = tid >> 6, lane = tid & 63;
    const int w0 = (bid - 3584) * 64 + wave * 16;
#pragma unroll 4
    for (int j = 0; j < 16; ++j) {
      float v = Mm[(size_t)(w0 + j) * 64 + lane];
      unsigned long long bl = __ballot(v != 0.0f);
      if (lane == 0) mpk[w0 + j] = bl;
    }
  } else {                                 // V transpose (b,h,64-token tile)
    const int idx = bid - 5632;
    const int t0 = (idx & 31) * 64, h = (idx >> 5) & 15, b = idx >> 9;
    const int sr = tid >> 3, sc = (tid & 7) * 8;
    const float* src = V + ((size_t)((b * S_ + t0) * H_ + h)) * HD_;
#pragma unroll
    for (int half = 0; half < 2; ++half) {
      const int r = sr + half * 32;
      float4 v0 = *(const float4*)&src[(size_t)r * (H_ * HD_) + sc];
      float4 v1 = *(const float4*)&src[(size_t)r * (H_ * HD_) + sc + 4];
      union { unsigned int w[4]; intx4 v; } p;
      p.w[0] = f2bf_pk(v0.x, v0.y); p.w[1] = f2bf_pk(v0.z, v0.w);
      p.w[2] = f2bf_pk(v1.x, v1.y); p.w[3] = f2bf_pk(v1.z, v1.w);
      *(intx4*)&tile[r * 72 + sc] = p.v;
    }
    __syncthreads();
    unsigned short* dst = vt + ((size_t)((b * H_ + h) * HD_)) * S_ + t0;
    union { unsigned short u[8]; intx4 v; } pack;
#pragma unroll
    for (int j = 0; j < 8; ++j) pack.u[j] = tile[(sc + j) * 72 + sr];
    *(intx4*)&dst[(size_t)sr * S_ + sc] = pack.v;
#pragma unroll
    for (int j = 0; j < 8; ++j) pack.u[j] = tile[(sc + j) * 72 + sr + 32];
    *(intx4*)&dst[(size_t)(sr + 32) * S_ + sc] = pack.v;
  }
}

// ---------------------------------------------------------------------------
// bf16 MFMA GEMM, templated tile: C = A @ Bm^T + bias. BK=32, wave grid 2x2,
// wave-tile (BM/2)x(BN/2), double-buffered staging (R8).
// R9: 1D grid 1024 with bijective XCD swizzle — XCD k (= blockIdx%8, HW
// round-robin) owns an 8x16 slab of the 16x64 tile grid, so its L2 working
// set (~2MB A-panel + ~2MB B-panel) fits the 4MB XCD L2 and panels are
// fetched once per XCD instead of ~8x. qscale: cols<1024 *= QSCALE.
// Grids must be 16 n-tiles x 64 m-tiles (both gemm1 and gemm2 are).
// ---------------------------------------------------------------------------
template<int BM, int BN>
__global__ __launch_bounds__(256) void gemm_tile(
    const unsigned short* __restrict__ A,
    const unsigned short* __restrict__ Bm,
    const float* __restrict__ bias,
    unsigned short* __restrict__ Cb, float* __restrict__ Cf,
    int N, int K, int qscale)
{
  constexpr int MT = BM / 32;    // 16x16 frags per wave in M (wave-tile BM/2)
  constexpr int NT = BN / 32;    // frags per wave in N (wave-tile BN/2)
  __shared__ unsigned short As[2][BM * 32];
  __shared__ unsigned short Bs[2][BN * 32];

  const int tid  = threadIdx.x;
  const int wave = tid >> 6, lane = tid & 63;
  const int quad = lane >> 4, l15 = lane & 15;
  const int wr = wave >> 1, wc = wave & 1;
  // XCD swizzle: L%8 = XCD; XCD (cx,cy) owns bx in [cx*8,cx*8+8),
  // by in [cy*16,cy*16+16). Bijective for grid 1024 = 16x64 tiles.
  const int L = blockIdx.x;
  const int xcd = L & 7, j = L >> 3;
  const int bxt = (xcd & 1) * 8 + (j & 7);
  const int byt = (xcd >> 1) * 16 + (j >> 3);
  const int bm = byt * BM, bn = bxt * BN;
  const int srow = tid >> 2, gs = tid & 3;

  auto stage = [&](int buf, int k0) {
#pragma unroll
    for (int r = 0; r < BM / 64; ++r) {
      const int row = srow + r * 64;
      gld16(&A[(size_t)(bm + row) * K + k0 + SW4(row, gs)],
            &As[buf][wave * 512 + r * 2048]);
    }
#pragma unroll
    for (int r = 0; r < BN / 64; ++r) {
      const int row = srow + r * 64;
      gld16(&Bm[(size_t)(bn + row) * K + k0 + SW4(row, gs)],
            &Bs[buf][wave * 512 + r * 2048]);
    }
  };

  floatx4 acc[MT][NT];
#pragma unroll
  for (int mt = 0; mt < MT; ++mt)
#pragma unroll
    for (int nt = 0; nt < NT; ++nt)
      acc[mt][nt] = (floatx4){0.f, 0.f, 0.f, 0.f};

  stage(0, 0);                       // prologue: tile 0 in flight

  const int KSTEPS = K / 32;
  for (int ks = 0; ks < KSTEPS; ++ks) {
    const int cur = ks & 1, nxt = cur ^ 1;
    asm volatile("s_waitcnt vmcnt(0)" ::: "memory");  // buf[cur] staged
    __syncthreads();  // all waves done reading buf[nxt] (step ks-1)

    if (ks + 1 < KSTEPS) stage(nxt, (ks + 1) * 32);   // prefetch step ks+1

    bf16x8 af[MT], bf[NT];
#pragma unroll
    for (int mt = 0; mt < MT; ++mt) {
      const int row = wr * (BM / 2) + mt * 16 + l15;
      af[mt] = *(const bf16x8*)&As[cur][row * 32 + SW4(row, quad)];
    }
#pragma unroll
    for (int nt = 0; nt < NT; ++nt) {
      const int row = wc * (BN / 2) + nt * 16 + l15;
      bf[nt] = *(const bf16x8*)&Bs[cur][row * 32 + SW4(row, quad)];
    }
    __builtin_amdgcn_s_setprio(1);
#pragma unroll
    for (int mt = 0; mt < MT; ++mt)
#pragma unroll
      for (int nt = 0; nt < NT; ++nt)
        acc[mt][nt] = mfma16(af[mt], bf[nt], acc[mt][nt]);
    __builtin_amdgcn_s_setprio(0);
  }

#pragma unroll
  for (int nt = 0; nt < NT; ++nt) {
    const int col = bn + wc * (BN / 2) + nt * 16 + l15;
    const float bi = bias[col];
    const float sc = (qscale && col < 1024) ? QSCALE : 1.0f;
#pragma unroll
    for (int mt = 0; mt < MT; ++mt) {
      const int row0 = bm + wr * (BM / 2) + mt * 16 + quad * 4;
#pragma unroll
      for (int reg = 0; reg < 4; ++reg) {
        const float v = (acc[mt][nt][reg] + bi) * sc;
        if (Cf) Cf[(size_t)(row0 + reg) * N + col] = v;
        else    Cb[(size_t)(row0 + reg) * N + col] = f2bf(v);
      }
    }
  }
}

// ---------------------------------------------------------------------------
// Fused masked-renorm attention: out = sum(e*M*V)/sum(e*M).
// R9 = R8 compute byte-identical; 1D grid 1024 with bijective XCD swizzle:
// XCD k owns 4 (b,h) pairs x 32 q-blocks, so each K/V panel (384KB) is
// fetched ~once per XCD L2 instead of ~4x from HBM (FETCH was 70MB vs
// ~18MB unique). Staging prefetches then hit L2 (~200cyc) not HBM (~900).
// ---------------------------------------------------------------------------
__global__ __launch_bounds__(256) void attn_kernel(
    const unsigned short* __restrict__ QK,      // [B*S][2048]
    const unsigned short* __restrict__ Vt,      // [B][H][HD][S]
    const unsigned long long* __restrict__ Mpk, // [B*S][S/64]
    unsigned short* __restrict__ ctx)           // [B*S][D]
{
  __shared__ unsigned short Ks[2][64 * 64];
  __shared__ unsigned short Vs[2][64 * 64];
  __shared__ unsigned long long Ms64[2][64];

  const int tid  = threadIdx.x;
  const int wave = tid >> 6, lane = tid & 63;
  const int quad = lane >> 4, l15 = lane & 15;
  // XCD swizzle: L%8 = XCD; pair p = (j>>5)*8 + xcd (4 pairs/XCD), qb = j&31.
  const int L = blockIdx.x;
  const int xcd = L & 7, j = L >> 3;
  const int pair = ((j >> 5) << 3) + xcd;      // 0..31
  const int b = pair >> 4, h = pair & 15;
  const int qb = (j & 31) * 64;
  const int gs = tid & 7;

  const unsigned short* Qbase = QK + (size_t)(b * S_ + qb) * 2048 + h * HD_;
  const unsigned short* Kbase = QK + (size_t)(b * S_) * 2048 + D_ + h * HD_;
  const unsigned short* Vbase = Vt + (size_t)((b * H_ + h) * HD_) * S_;
  const unsigned long long* Mbase = Mpk + (size_t)(b * S_ + qb) * (S_ / 64);

  // ---- stage Q (64x64, stride 64) into the Ks[0] region ----
  unsigned short* Qs = &Ks[0][0];
#pragma unroll
  for (int r = 0; r < 2; ++r) {
    const int row = (tid >> 3) + r * 32;
    gld16(Qbase + (size_t)row * 2048 + SW8(row, gs), Qs + wave * 512 + r * 2048);
  }
  if (tid < 64) Ms64[0][tid] = Mbase[(size_t)tid * (S_ / 64)];
  asm volatile("s_waitcnt vmcnt(0)" ::: "memory");
  __syncthreads();

  // loop-invariant Q fragments (rows wave*16..+15)
  bf16x8 qf[2];
#pragma unroll
  for (int c = 0; c < 2; ++c) {
    const int row = wave * 16 + l15;
    qf[c] = *(const bf16x8*)&Qs[row * 64 + SW8(row, c * 4 + quad)];
  }
  __syncthreads();   // all qf reads done before K tile-0 staging overwrites

  // ---- stage tile 0 K (TAU-permuted rows) and V ----
#pragma unroll
  for (int r = 0; r < 2; ++r) {
    const int rowd = (tid >> 3) + r * 32;
    const int tokK = TAU(rowd);
    gld16(Kbase + (size_t)tokK * 2048 + SW8(rowd, gs), &Ks[0][wave * 512 + r * 2048]);
    gld16(Vbase + (size_t)rowd * S_ + SW8(rowd, gs),   &Vs[0][wave * 512 + r * 2048]);
  }

  floatx4 accO[4];
  float Pp = 0.f;
#pragma unroll
  for (int nt = 0; nt < 4; ++nt)
    accO[nt] = (floatx4){0.f, 0.f, 0.f, 0.f};

  const int q8 = quad * 8;

  for (int i = 0; i < 32; ++i) {
    const int cur = i & 1, nxt = cur ^ 1;
    asm volatile("s_waitcnt vmcnt(0)" ::: "memory");  // buf[cur] staged
    __syncthreads();  // all waves done with buf[nxt] (tile i-1)

    if (i + 1 < 32) {  // prefetch tile i+1
      const int t1 = (i + 1) * 64;
#pragma unroll
      for (int r = 0; r < 2; ++r) {
        const int rowd = (tid >> 3) + r * 32;
        const int tokK = TAU(rowd);
        gld16(Kbase + (size_t)(t1 + tokK) * 2048 + SW8(rowd, gs),
              &Ks[nxt][wave * 512 + r * 2048]);
        gld16(Vbase + (size_t)rowd * S_ + t1 + SW8(rowd, gs),
              &Vs[nxt][wave * 512 + r * 2048]);
      }
      if (tid < 64)
        Ms64[nxt][tid] = Mbase[(size_t)tid * (S_ / 64) + i + 1];
    }

    // S^T = K @ Q^T (swapped operands): lane l15 = q-row, quad/reg = token
    floatx4 sc[4];
    __builtin_amdgcn_s_setprio(1);
#pragma unroll
    for (int nt = 0; nt < 4; ++nt) {
      const int row = nt * 16 + l15;
      bf16x8 kf0 = *(const bf16x8*)&Ks[cur][row * 64 + SW8(row, quad)];
      bf16x8 kf1 = *(const bf16x8*)&Ks[cur][row * 64 + SW8(row, 4 + quad)];
      floatx4 z = (floatx4){0.f, 0.f, 0.f, 0.f};
      z = mfma16(kf0, qf[0], z);
      z = mfma16(kf1, qf[1], z);
      sc[nt] = z;
    }
    __builtin_amdgcn_s_setprio(0);

    // mask word: one 64-bit word per q-row (lane-local q = l15), pre-shifted
    const unsigned long long mw = Ms64[cur][wave * 16 + l15];
    const unsigned int w_lo = ((unsigned int)mw) >> q8;
    const unsigned int w_hi = ((unsigned int)(mw >> 32)) >> q8;

    // V fragments — independent of P, hoisted above the softmax
    bf16x8 vf0[4], vf1[4];
#pragma unroll
    for (int nt = 0; nt < 4; ++nt) {
      const int row = nt * 16 + l15;
      vf0[nt] = *(const bf16x8*)&Vs[cur][row * 64 + SW8(row, quad)];
      vf1[nt] = *(const bf16x8*)&Vs[cur][row * 64 + SW8(row, 4 + quad)];
    }

    // softmax: exp2 + sbfe/and mask, pack straight into PV A-frags
    bf16x8 pa0, pa1;
    {
      union { unsigned int w[4]; bf16x8 v; } A0, A1;
#pragma unroll
      for (int nt = 0; nt < 4; ++nt) {
        const unsigned int ws = (nt < 2) ? w_lo : w_hi;
        float p[4];
#pragma unroll
        for (int reg = 0; reg < 4; ++reg) {
          const int j2 = (nt & 1) * 4 + reg;     // bit 0..7 of ws
          const float e = EXP2(sc[nt][reg]);
          const int m = SBFE1(ws, j2);            // 0 or -1
          p[reg] = __uint_as_float(__float_as_uint(e) & (unsigned int)m);
        }
        Pp += (p[0] + p[1]) + (p[2] + p[3]);
        const unsigned int d0 = f2bf_pk(p[0], p[1]);
        const unsigned int d1 = f2bf_pk(p[2], p[3]);
        if (nt == 0)      { A0.w[0] = d0; A0.w[1] = d1; }
        else if (nt == 1) { A0.w[2] = d0; A0.w[3] = d1; }
        else if (nt == 2) { A1.w[0] = d0; A1.w[1] = d1; }
        else              { A1.w[2] = d0; A1.w[3] = d1; }
      }
      pa0 = A0.v; pa1 = A1.v;
    }

    // O += P @ V^T (P already in A-frag layout)
    __builtin_amdgcn_s_setprio(1);
#pragma unroll
    for (int nt = 0; nt < 4; ++nt) {
      accO[nt] = mfma16(pa0, vf0[nt], accO[nt]);
      accO[nt] = mfma16(pa1, vf1[nt], accO[nt]);
    }
    __builtin_amdgcn_s_setprio(0);
  }

  // Pp: lane (quad,l15) holds partial row-sum for q-row l15 over that quad's
  // tokens. Reduce over quads (lane^16, lane^32).
  Pp += __shfl_xor(Pp, 16);
  Pp += __shfl_xor(Pp, 32);
  Pp = 1.0f / (Pp + 1e-30f);
  // redistribute: epilogue needs inv-sum for q-row quad*4 + reg
  float Ppe[4];
#pragma unroll
  for (int reg = 0; reg < 4; ++reg)
    Ppe[reg] = __shfl(Pp, (quad << 4) | (quad * 4 + reg));

#pragma unroll
  for (int nt = 0; nt < 4; ++nt)
#pragma unroll
    for (int reg = 0; reg < 4; ++reg) {
      const int row = wave * 16 + quad * 4 + reg;
      ctx[(size_t)(b * S_ + qb + row) * D_ + h * HD_ + nt * 16 + l15] =
          f2bf(accO[nt][reg] * Ppe[reg]);
    }
}

// ---------------------------------------------------------------------------
extern "C" void kernel_launch(void* const* d_in, const int* in_sizes, int n_in,
                              void* d_out, int out_size, void* d_ws, size_t ws_size,
                              hipStream_t stream) {
  const float* x     = (const float*)d_in[0];
  const float* V     = (const float*)d_in[1];
  const float* Mm    = (const float*)d_in[2];
  const float* w_in  = (const float*)d_in[3];
  const float* b_in  = (const float*)d_in[4];
  const float* w_out = (const float*)d_in[5];
  const float* b_out = (const float*)d_in[6];
  float* out = (float*)d_out;                  // fp32 (verified R5)

  // workspace layout (ushort units)
  unsigned short* qk  = (unsigned short*)d_ws;          // 8M   [4096][2048]
  unsigned short* vt  = qk  + (size_t)8 * 1024 * 1024;  // 4M   [B][H][HD][S]
  unsigned short* ctx = vt  + (size_t)4 * 1024 * 1024;  // 4M   [4096][1024]
  unsigned short* xb  = ctx + (size_t)4 * 1024 * 1024;  // 4M   bf16(x)
  unsigned short* wb  = xb  + (size_t)4 * 1024 * 1024;  // 2M   bf16(w_in[0:2048])
  unsigned short* wob = wb  + (size_t)2 * 1024 * 1024;  // 1M   bf16(out_w)
  unsigned long long* mpk = (unsigned long long*)(wob + (size_t)1024 * 1024);

  // 0) fused prep: converts + mask pack + V transpose (one dispatch)
  prep_kernel<<<6656, 256, 0, stream>>>(x, w_in, w_out, V, Mm,
                                        xb, wb, wob, vt, mpk);

  // 1) QK = x @ in_proj_w[0:2048]^T + b_in; Q cols pre-scaled by QSCALE
  //    64x128 tile, dbuf staging, XCD-swizzled 1D grid (16x64 tiles)
  gemm_tile<64, 128><<<1024, 256, 0, stream>>>(
      xb, wb, b_in, qk, nullptr, 2048, D_, 1);

  // 2) fused masked-renorm attention -> ctx (bf16), XCD-swizzled 1D grid
  attn_kernel<<<1024, 256, 0, stream>>>(qk, vt, mpk, ctx);

  // 3) out = ctx @ out_w^T + out_b  (fp32 store to d_out)
  //    64x64 tile, dbuf staging, XCD-swizzled 1D grid (16x64 tiles)
  gemm_tile<64, 64><<<1024, 256, 0, stream>>>(
      ctx, wob, b_out, nullptr, out, D_, D_, 0);
}